// Round 8
// baseline (496.356 us; speedup 1.0000x reference)
//
#include <hip/hip_runtime.h>
#include <math.h>
#include <float.h>

#define NNODES 50000
#define NEDGES 800000
#define NSCANB ((NNODES + 255) / 256)   // 196
// feature dims: in=hid=out=128, heads=4, head_dim=32

// ---------------- CSR build ----------------
__global__ __launch_bounds__(256) void hist_kernel(const int* __restrict__ dst,
                                                   int* __restrict__ deg) {
    int e = blockIdx.x * 256 + threadIdx.x;
    if (e < NEDGES) atomicAdd(&deg[dst[e]], 1);
}

__global__ __launch_bounds__(256) void scan1_kernel(const int* __restrict__ deg,
                                                    int* __restrict__ bsum) {
    int i = blockIdx.x * 256 + threadIdx.x;
    int t = threadIdx.x, lane = t & 63, w = t >> 6;
    int v = (i < NNODES) ? deg[i] : 0;
    int x = v;
#pragma unroll
    for (int off = 1; off < 64; off <<= 1) x += __shfl_xor(x, off);
    __shared__ int wtot[4];
    if (lane == 0) wtot[w] = x;
    __syncthreads();
    if (t == 0) bsum[blockIdx.x] = wtot[0] + wtot[1] + wtot[2] + wtot[3];
}

__global__ __launch_bounds__(256) void scan2_kernel(const int* __restrict__ bsum,
                                                    int* __restrict__ boff,
                                                    int* __restrict__ roff) {
    __shared__ int s[256];
    int t = threadIdx.x;
    int v = (t < NSCANB) ? bsum[t] : 0;
    s[t] = v;
    __syncthreads();
    for (int off = 1; off < 256; off <<= 1) {
        int y = (t >= off) ? s[t - off] : 0;
        __syncthreads();
        s[t] += y;
        __syncthreads();
    }
    if (t < NSCANB) boff[t] = s[t] - v;
    if (t == 255) roff[NNODES] = s[255];
}

__global__ __launch_bounds__(256) void scan3_kernel(const int* __restrict__ deg,
                                                    const int* __restrict__ boff,
                                                    int* __restrict__ roff,
                                                    int* __restrict__ cursor) {
    int i = blockIdx.x * 256 + threadIdx.x;
    int t = threadIdx.x, lane = t & 63, w = t >> 6;
    int v = (i < NNODES) ? deg[i] : 0;
    int x = v;
#pragma unroll
    for (int off = 1; off < 64; off <<= 1) {
        int y = __shfl_up(x, off, 64);
        if (lane >= off) x += y;
    }
    __shared__ int wtot[4];
    if (lane == 63) wtot[w] = x;
    __syncthreads();
    int wpre = 0;
#pragma unroll
    for (int j = 0; j < 4; ++j) if (j < w) wpre += wtot[j];
    int ex = boff[blockIdx.x] + wpre + x - v;
    if (i < NNODES) { roff[i] = ex; cursor[i] = ex; }
}

__global__ __launch_bounds__(256) void bucket_kernel(const int* __restrict__ src,
                                                     const int* __restrict__ dst,
                                                     int* __restrict__ cursor,
                                                     int* __restrict__ csr_src) {
    int e = blockIdx.x * 256 + threadIdx.x;
    if (e >= NEDGES) return;
    int d = dst[e];
    int pos = atomicAdd(&cursor[d], 1);
    csr_src[pos] = src[e];
}

// ---------------- GEMM + alpha: h = X@W ; alpha_s/d = <h, a_src/dst> -------
// 128-row tile, 256 threads, 8x8 acc per thread.
#define GBM 128
#define GBK 32
__global__ __launch_bounds__(256) void gemm_alpha_kernel(
    const float* __restrict__ X, const float* __restrict__ W,
    const float* __restrict__ avs, const float* __restrict__ avd,
    float* __restrict__ Hh, float* __restrict__ alpha_s, float* __restrict__ alpha_d,
    int nrows)
{
    __shared__ float Xs[GBK][GBM];   // transposed X tile: Xs[k][row], 16KB
    __shared__ float Ws[GBK][128];   // W tile: Ws[k][col], 16KB

    int t = threadIdx.x;
    int row0 = (t >> 4) * 8;         // 0..120
    int col0 = (t & 15) * 8;         // 0..120
    int block_row = blockIdx.x * GBM;

    float acc[8][8];
#pragma unroll
    for (int i = 0; i < 8; ++i)
#pragma unroll
        for (int j = 0; j < 8; ++j) acc[i][j] = 0.f;

    for (int k0 = 0; k0 < 128; k0 += GBK) {
        {
            int r  = t >> 1;               // 0..127
            int kb = (t & 1) * 16;         // 0 or 16
            int grow = block_row + r;
            float4 v0 = make_float4(0,0,0,0), v1 = v0, v2 = v0, v3 = v0;
            if (grow < nrows) {
                const float* p = X + (size_t)grow * 128 + k0 + kb;
                v0 = ((const float4*)p)[0];
                v1 = ((const float4*)p)[1];
                v2 = ((const float4*)p)[2];
                v3 = ((const float4*)p)[3];
            }
            Xs[kb+ 0][r] = v0.x; Xs[kb+ 1][r] = v0.y; Xs[kb+ 2][r] = v0.z; Xs[kb+ 3][r] = v0.w;
            Xs[kb+ 4][r] = v1.x; Xs[kb+ 5][r] = v1.y; Xs[kb+ 6][r] = v1.z; Xs[kb+ 7][r] = v1.w;
            Xs[kb+ 8][r] = v2.x; Xs[kb+ 9][r] = v2.y; Xs[kb+10][r] = v2.z; Xs[kb+11][r] = v2.w;
            Xs[kb+12][r] = v3.x; Xs[kb+13][r] = v3.y; Xs[kb+14][r] = v3.z; Xs[kb+15][r] = v3.w;
        }
        {
            int kr = t >> 3;               // 0..31
            int cc = (t & 7) * 16;         // 0..112
            const float* p = W + (size_t)(k0 + kr) * 128 + cc;
            float4 w0 = ((const float4*)p)[0];
            float4 w1 = ((const float4*)p)[1];
            float4 w2 = ((const float4*)p)[2];
            float4 w3 = ((const float4*)p)[3];
            *(float4*)&Ws[kr][cc + 0]  = w0;
            *(float4*)&Ws[kr][cc + 4]  = w1;
            *(float4*)&Ws[kr][cc + 8]  = w2;
            *(float4*)&Ws[kr][cc + 12] = w3;
        }
        __syncthreads();
#pragma unroll
        for (int kk = 0; kk < GBK; ++kk) {
            float4 a0 = *(const float4*)&Xs[kk][row0];
            float4 a1 = *(const float4*)&Xs[kk][row0 + 4];
            float4 w0 = *(const float4*)&Ws[kk][col0];
            float4 w1 = *(const float4*)&Ws[kk][col0 + 4];
            float av[8] = {a0.x, a0.y, a0.z, a0.w, a1.x, a1.y, a1.z, a1.w};
            float wv[8] = {w0.x, w0.y, w0.z, w0.w, w1.x, w1.y, w1.z, w1.w};
#pragma unroll
            for (int i = 0; i < 8; ++i)
#pragma unroll
                for (int j = 0; j < 8; ++j)
                    acc[i][j] = fmaf(av[i], wv[j], acc[i][j]);
        }
        __syncthreads();
    }

    int cg = t & 15;
    int head = cg >> 2;                       // col0/32
    const float* asrc = avs + head * 32 + (cg & 3) * 8;
    const float* adst = avd + head * 32 + (cg & 3) * 8;
#pragma unroll
    for (int i = 0; i < 8; ++i) {
        int grow = block_row + row0 + i;
        bool ok = (grow < nrows);
        if (ok) {
            float4 o0 = make_float4(acc[i][0], acc[i][1], acc[i][2], acc[i][3]);
            float4 o1 = make_float4(acc[i][4], acc[i][5], acc[i][6], acc[i][7]);
            *(float4*)&Hh[(size_t)grow * 128 + col0]     = o0;
            *(float4*)&Hh[(size_t)grow * 128 + col0 + 4] = o1;
        }
        float ps = 0.f, pd = 0.f;
#pragma unroll
        for (int j = 0; j < 8; ++j) {
            ps = fmaf(acc[i][j], asrc[j], ps);
            pd = fmaf(acc[i][j], adst[j], pd);
        }
        ps += __shfl_xor(ps, 1); ps += __shfl_xor(ps, 2);
        pd += __shfl_xor(pd, 1); pd += __shfl_xor(pd, 2);
        if (ok && (cg & 3) == 0) {
            alpha_s[grow * 4 + head] = ps;
            alpha_d[grow * 4 + head] = pd;
        }
    }
}

// ------- fused attention + gather, XCD-sharded feature slices --------------
// Block b handles (node group = b>>3, feature slice = b&7). Workgroup
// dispatch round-robins blockIdx across the 8 XCDs, so all blocks reading
// feature-slice k run on XCD k: that XCD's L2 working set of h is only
// 50000*16*4B = 3.2MB -> fits the 4MB per-XCD L2 and stays hot. (If the
// mapping assumption fails this is merely perf-neutral.)
// Each block: 256 threads = 4 waves = 4 consecutive nodes, same slice.
// Wave lanes: parity p = lane>>4 strides edges by 4; ft = lane&15 is the
// feature within the slice (64B coalesced h reads per parity). exp is
// SIMD-redundant across the 16 feature lanes (free) and one v_exp covers
// 4 edges. No max-shift (logits O(+-6), softmax shift-invariant).
// Parity partials combined via shfl_xor(16)+shfl_xor(32).
__global__ __launch_bounds__(256) void att_gather_kernel(
    const int* __restrict__ csr_src, const int* __restrict__ roff,
    const float* __restrict__ alpha_s, const float* __restrict__ alpha_d,
    const float* __restrict__ hbuf, const float* __restrict__ b,
    float* __restrict__ out)
{
    int blk   = blockIdx.x;
    int slice = blk & 7;
    int ngrp  = blk >> 3;
    int wid   = threadIdx.x >> 6;
    int node  = ngrp * 4 + wid;
    if (node >= NNODES) return;
    int lane = threadIdx.x & 63;
    int p    = lane >> 4;            // edge parity 0..3
    int ft   = lane & 15;            // feature within slice
    int f    = slice * 16 + ft;      // global feature 0..127
    int hh   = f >> 5;               // head
    int beg = roff[node], end = roff[node + 1];
    float ad = alpha_d[node * 4 + hh];

    float acc = 0.f, den = 0.f;
    int i = beg + p;
    for (; i + 4 < end; i += 8) {    // 2 independent edges per lane/iter
        int s0 = csr_src[i];
        int s1 = csr_src[i + 4];
        float l0 = alpha_s[s0 * 4 + hh] + ad;
        float l1 = alpha_s[s1 * 4 + hh] + ad;
        l0 = (l0 >= 0.f) ? l0 : 0.2f * l0;
        l1 = (l1 >= 0.f) ? l1 : 0.2f * l1;
        float e0 = __expf(l0);
        float e1 = __expf(l1);
        float h0 = hbuf[(size_t)s0 * 128 + f];
        float h1 = hbuf[(size_t)s1 * 128 + f];
        den += e0 + e1;
        acc = fmaf(e0, h0, acc);
        acc = fmaf(e1, h1, acc);
    }
    if (i < end) {
        int s0 = csr_src[i];
        float l0 = alpha_s[s0 * 4 + hh] + ad;
        l0 = (l0 >= 0.f) ? l0 : 0.2f * l0;
        float e0 = __expf(l0);
        float h0 = hbuf[(size_t)s0 * 128 + f];
        den += e0;
        acc = fmaf(e0, h0, acc);
    }

    // combine the 4 parities (lane bits 4,5)
    acc += __shfl_xor(acc, 16);
    acc += __shfl_xor(acc, 32);
    den += __shfl_xor(den, 16);
    den += __shfl_xor(den, 32);

    if (p == 0) {
        float x = acc / fmaxf(den, 1e-16f) + b[f];
        out[(size_t)node * 128 + f] = (x > 0.f) ? x : expm1f(x);
    }
}

extern "C" void kernel_launch(void* const* d_in, const int* in_sizes, int n_in,
                              void* d_out, int out_size, void* d_ws, size_t ws_size,
                              hipStream_t stream) {
    const float* X    = (const float*)d_in[0];
    const int*   ei   = (const int*)d_in[1];
    const float* W0   = (const float*)d_in[2];
    const float* as0  = (const float*)d_in[3];
    const float* ad0  = (const float*)d_in[4];
    const float* b0   = (const float*)d_in[5];
    const float* W1   = (const float*)d_in[6];
    const float* as1  = (const float*)d_in[7];
    const float* ad1  = (const float*)d_in[8];
    const float* b1   = (const float*)d_in[9];

    const int* srcp = ei;            // edge_index[0]
    const int* dstp = ei + NEDGES;   // edge_index[1]

    float* ws = (float*)d_ws;
    float* h    = ws;                        // 6,400,000 floats
    float* hout = h    + 6400000;            // 6,400,000
    float* as_  = hout + 6400000;            // 200,000
    float* ad_  = as_  + 200000;             // 200,000
    int*   deg     = (int*)(ad_ + 200000);   // 50,000 ints
    int*   roff    = deg + 50000;            // 50,001
    int*   cursor  = roff + 50001;           // 50,000
    int*   csr_src = cursor + 50000;         // 800,000
    int*   bsum    = csr_src + 800000;       // 196
    int*   boff    = bsum + NSCANB;          // 196

    // ---- CSR build (by destination), layer-invariant ----
    hipMemsetAsync(deg, 0, NNODES * sizeof(int), stream);
    hist_kernel<<<(NEDGES + 255) / 256, 256, 0, stream>>>(dstp, deg);
    scan1_kernel<<<NSCANB, 256, 0, stream>>>(deg, bsum);
    scan2_kernel<<<1, 256, 0, stream>>>(bsum, boff, roff);
    scan3_kernel<<<NSCANB, 256, 0, stream>>>(deg, boff, roff, cursor);
    bucket_kernel<<<(NEDGES + 255) / 256, 256, 0, stream>>>(srcp, dstp, cursor, csr_src);

    const int NODE_BLOCKS = ((NNODES + 3) / 4) * 8;   // (node-group, slice)

    for (int layer = 0; layer < 2; ++layer) {
        const float* Hin = layer ? hout : X;
        const float* W   = layer ? W1  : W0;
        const float* avs = layer ? as1 : as0;
        const float* avd = layer ? ad1 : ad0;
        const float* bv  = layer ? b1  : b0;
        float* outp      = layer ? (float*)d_out : hout;

        gemm_alpha_kernel<<<(NNODES + GBM - 1) / GBM, 256, 0, stream>>>(
            Hin, W, avs, avd, h, as_, ad_, NNODES);

        att_gather_kernel<<<NODE_BLOCKS, 256, 0, stream>>>(
            csr_src, roff, as_, ad_, h, bv, outp);
    }
}

// Round 9
// 286.519 us; speedup vs baseline: 1.7324x; 1.7324x over previous
//
#include <hip/hip_runtime.h>
#include <math.h>
#include <float.h>

#define NNODES 50000
#define NEDGES 800000
#define NSCANB ((NNODES + 255) / 256)   // 196
// feature dims: in=hid=out=128, heads=4, head_dim=32

// ---------------- CSR build ----------------
__global__ __launch_bounds__(256) void hist_kernel(const int* __restrict__ dst,
                                                   int* __restrict__ deg) {
    int e = blockIdx.x * 256 + threadIdx.x;
    if (e < NEDGES) atomicAdd(&deg[dst[e]], 1);
}

__global__ __launch_bounds__(256) void scan1_kernel(const int* __restrict__ deg,
                                                    int* __restrict__ bsum) {
    int i = blockIdx.x * 256 + threadIdx.x;
    int t = threadIdx.x, lane = t & 63, w = t >> 6;
    int v = (i < NNODES) ? deg[i] : 0;
    int x = v;
#pragma unroll
    for (int off = 1; off < 64; off <<= 1) x += __shfl_xor(x, off);
    __shared__ int wtot[4];
    if (lane == 0) wtot[w] = x;
    __syncthreads();
    if (t == 0) bsum[blockIdx.x] = wtot[0] + wtot[1] + wtot[2] + wtot[3];
}

__global__ __launch_bounds__(256) void scan2_kernel(const int* __restrict__ bsum,
                                                    int* __restrict__ boff,
                                                    int* __restrict__ roff) {
    __shared__ int s[256];
    int t = threadIdx.x;
    int v = (t < NSCANB) ? bsum[t] : 0;
    s[t] = v;
    __syncthreads();
    for (int off = 1; off < 256; off <<= 1) {
        int y = (t >= off) ? s[t - off] : 0;
        __syncthreads();
        s[t] += y;
        __syncthreads();
    }
    if (t < NSCANB) boff[t] = s[t] - v;
    if (t == 255) roff[NNODES] = s[255];
}

__global__ __launch_bounds__(256) void scan3_kernel(const int* __restrict__ deg,
                                                    const int* __restrict__ boff,
                                                    int* __restrict__ roff,
                                                    int* __restrict__ cursor) {
    int i = blockIdx.x * 256 + threadIdx.x;
    int t = threadIdx.x, lane = t & 63, w = t >> 6;
    int v = (i < NNODES) ? deg[i] : 0;
    int x = v;
#pragma unroll
    for (int off = 1; off < 64; off <<= 1) {
        int y = __shfl_up(x, off, 64);
        if (lane >= off) x += y;
    }
    __shared__ int wtot[4];
    if (lane == 63) wtot[w] = x;
    __syncthreads();
    int wpre = 0;
#pragma unroll
    for (int j = 0; j < 4; ++j) if (j < w) wpre += wtot[j];
    int ex = boff[blockIdx.x] + wpre + x - v;
    if (i < NNODES) { roff[i] = ex; cursor[i] = ex; }
}

__global__ __launch_bounds__(256) void bucket_kernel(const int* __restrict__ src,
                                                     const int* __restrict__ dst,
                                                     int* __restrict__ cursor,
                                                     int* __restrict__ csr_src) {
    int e = blockIdx.x * 256 + threadIdx.x;
    if (e >= NEDGES) return;
    int d = dst[e];
    int pos = atomicAdd(&cursor[d], 1);
    csr_src[pos] = src[e];
}

// ---------------- GEMM + alpha: h = X@W ; alpha_s/d = <h, a_src/dst> -------
// 128-row tile, 256 threads, 8x8 acc per thread.
#define GBM 128
#define GBK 32
__global__ __launch_bounds__(256) void gemm_alpha_kernel(
    const float* __restrict__ X, const float* __restrict__ W,
    const float* __restrict__ avs, const float* __restrict__ avd,
    float* __restrict__ Hh, float* __restrict__ alpha_s, float* __restrict__ alpha_d,
    int nrows)
{
    __shared__ float Xs[GBK][GBM];   // transposed X tile: Xs[k][row], 16KB
    __shared__ float Ws[GBK][128];   // W tile: Ws[k][col], 16KB

    int t = threadIdx.x;
    int row0 = (t >> 4) * 8;         // 0..120
    int col0 = (t & 15) * 8;         // 0..120
    int block_row = blockIdx.x * GBM;

    float acc[8][8];
#pragma unroll
    for (int i = 0; i < 8; ++i)
#pragma unroll
        for (int j = 0; j < 8; ++j) acc[i][j] = 0.f;

    for (int k0 = 0; k0 < 128; k0 += GBK) {
        {
            int r  = t >> 1;               // 0..127
            int kb = (t & 1) * 16;         // 0 or 16
            int grow = block_row + r;
            float4 v0 = make_float4(0,0,0,0), v1 = v0, v2 = v0, v3 = v0;
            if (grow < nrows) {
                const float* p = X + (size_t)grow * 128 + k0 + kb;
                v0 = ((const float4*)p)[0];
                v1 = ((const float4*)p)[1];
                v2 = ((const float4*)p)[2];
                v3 = ((const float4*)p)[3];
            }
            Xs[kb+ 0][r] = v0.x; Xs[kb+ 1][r] = v0.y; Xs[kb+ 2][r] = v0.z; Xs[kb+ 3][r] = v0.w;
            Xs[kb+ 4][r] = v1.x; Xs[kb+ 5][r] = v1.y; Xs[kb+ 6][r] = v1.z; Xs[kb+ 7][r] = v1.w;
            Xs[kb+ 8][r] = v2.x; Xs[kb+ 9][r] = v2.y; Xs[kb+10][r] = v2.z; Xs[kb+11][r] = v2.w;
            Xs[kb+12][r] = v3.x; Xs[kb+13][r] = v3.y; Xs[kb+14][r] = v3.z; Xs[kb+15][r] = v3.w;
        }
        {
            int kr = t >> 3;               // 0..31
            int cc = (t & 7) * 16;         // 0..112
            const float* p = W + (size_t)(k0 + kr) * 128 + cc;
            float4 w0 = ((const float4*)p)[0];
            float4 w1 = ((const float4*)p)[1];
            float4 w2 = ((const float4*)p)[2];
            float4 w3 = ((const float4*)p)[3];
            *(float4*)&Ws[kr][cc + 0]  = w0;
            *(float4*)&Ws[kr][cc + 4]  = w1;
            *(float4*)&Ws[kr][cc + 8]  = w2;
            *(float4*)&Ws[kr][cc + 12] = w3;
        }
        __syncthreads();
#pragma unroll
        for (int kk = 0; kk < GBK; ++kk) {
            float4 a0 = *(const float4*)&Xs[kk][row0];
            float4 a1 = *(const float4*)&Xs[kk][row0 + 4];
            float4 w0 = *(const float4*)&Ws[kk][col0];
            float4 w1 = *(const float4*)&Ws[kk][col0 + 4];
            float av[8] = {a0.x, a0.y, a0.z, a0.w, a1.x, a1.y, a1.z, a1.w};
            float wv[8] = {w0.x, w0.y, w0.z, w0.w, w1.x, w1.y, w1.z, w1.w};
#pragma unroll
            for (int i = 0; i < 8; ++i)
#pragma unroll
                for (int j = 0; j < 8; ++j)
                    acc[i][j] = fmaf(av[i], wv[j], acc[i][j]);
        }
        __syncthreads();
    }

    int cg = t & 15;
    int head = cg >> 2;                       // col0/32
    const float* asrc = avs + head * 32 + (cg & 3) * 8;
    const float* adst = avd + head * 32 + (cg & 3) * 8;
#pragma unroll
    for (int i = 0; i < 8; ++i) {
        int grow = block_row + row0 + i;
        bool ok = (grow < nrows);
        if (ok) {
            float4 o0 = make_float4(acc[i][0], acc[i][1], acc[i][2], acc[i][3]);
            float4 o1 = make_float4(acc[i][4], acc[i][5], acc[i][6], acc[i][7]);
            *(float4*)&Hh[(size_t)grow * 128 + col0]     = o0;
            *(float4*)&Hh[(size_t)grow * 128 + col0 + 4] = o1;
        }
        float ps = 0.f, pd = 0.f;
#pragma unroll
        for (int j = 0; j < 8; ++j) {
            ps = fmaf(acc[i][j], asrc[j], ps);
            pd = fmaf(acc[i][j], adst[j], pd);
        }
        ps += __shfl_xor(ps, 1); ps += __shfl_xor(ps, 2);
        pd += __shfl_xor(pd, 1); pd += __shfl_xor(pd, 2);
        if (ok && (cg & 3) == 0) {
            alpha_s[grow * 4 + head] = ps;
            alpha_d[grow * 4 + head] = pd;
        }
    }
}

// ------- fused attention + gather, SINGLE PASS, no LDS, unroll-4 ----------
// out = elu( (sum_e ex_e * h[src_e]) / (sum_e ex_e) + b ),
// ex_e = exp(leakyrelu(alpha_s[src_e] + alpha_d[node]))  (no max-shift:
// logits are O(+-6), exp fp32-safe, softmax shift-invariant).
// One wave per node. half = lane>>5 handles edges of parity `half`; lane owns
// features q*4..q*4+3 (q = lane&31): 32 lanes x 16B = full 512B h row per
// edge. 4 independent edges per half-wave iteration (8 in flight per wave)
// to cover L2/LLC-miss latency. den accumulated alongside; both halves
// combined with one shfl_xor(32); normalize once at the end.
__global__ __launch_bounds__(256) void att_gather_kernel(
    const int* __restrict__ csr_src, const int* __restrict__ roff,
    const float* __restrict__ alpha_s, const float* __restrict__ alpha_d,
    const float* __restrict__ hbuf, const float* __restrict__ b,
    float* __restrict__ out)
{
    int node = blockIdx.x * 4 + (threadIdx.x >> 6);
    if (node >= NNODES) return;
    int lane = threadIdx.x & 63;
    int half = lane >> 5;               // edge parity this lane handles
    int q    = lane & 31;
    int f    = q * 4;                   // features f..f+3
    int hh   = q >> 3;                  // head owning features f..f+3
    int beg = roff[node], end = roff[node + 1];
    float ad = alpha_d[node * 4 + hh];

    float4 a4 = make_float4(0.f, 0.f, 0.f, 0.f);
    float den = 0.f;
    int i = beg + half;
    for (; i + 6 < end; i += 8) {       // 4 independent edges per lane/iter
        int s0 = csr_src[i];
        int s1 = csr_src[i + 2];
        int s2 = csr_src[i + 4];
        int s3 = csr_src[i + 6];
        float l0 = alpha_s[s0 * 4 + hh] + ad;
        float l1 = alpha_s[s1 * 4 + hh] + ad;
        float l2 = alpha_s[s2 * 4 + hh] + ad;
        float l3 = alpha_s[s3 * 4 + hh] + ad;
        float4 h0 = *(const float4*)(hbuf + (size_t)s0 * 128 + f);
        float4 h1 = *(const float4*)(hbuf + (size_t)s1 * 128 + f);
        float4 h2 = *(const float4*)(hbuf + (size_t)s2 * 128 + f);
        float4 h3 = *(const float4*)(hbuf + (size_t)s3 * 128 + f);
        l0 = (l0 >= 0.f) ? l0 : 0.2f * l0;
        l1 = (l1 >= 0.f) ? l1 : 0.2f * l1;
        l2 = (l2 >= 0.f) ? l2 : 0.2f * l2;
        l3 = (l3 >= 0.f) ? l3 : 0.2f * l3;
        float e0 = __expf(l0);
        float e1 = __expf(l1);
        float e2 = __expf(l2);
        float e3 = __expf(l3);
        den += (e0 + e1) + (e2 + e3);
        a4.x = fmaf(e0, h0.x, a4.x); a4.y = fmaf(e0, h0.y, a4.y);
        a4.z = fmaf(e0, h0.z, a4.z); a4.w = fmaf(e0, h0.w, a4.w);
        a4.x = fmaf(e1, h1.x, a4.x); a4.y = fmaf(e1, h1.y, a4.y);
        a4.z = fmaf(e1, h1.z, a4.z); a4.w = fmaf(e1, h1.w, a4.w);
        a4.x = fmaf(e2, h2.x, a4.x); a4.y = fmaf(e2, h2.y, a4.y);
        a4.z = fmaf(e2, h2.z, a4.z); a4.w = fmaf(e2, h2.w, a4.w);
        a4.x = fmaf(e3, h3.x, a4.x); a4.y = fmaf(e3, h3.y, a4.y);
        a4.z = fmaf(e3, h3.z, a4.z); a4.w = fmaf(e3, h3.w, a4.w);
    }
    for (; i < end; i += 2) {           // tail: 0..3 edges of this parity
        int s0 = csr_src[i];
        float l0 = alpha_s[s0 * 4 + hh] + ad;
        l0 = (l0 >= 0.f) ? l0 : 0.2f * l0;
        float e0 = __expf(l0);
        float4 h0 = *(const float4*)(hbuf + (size_t)s0 * 128 + f);
        den += e0;
        a4.x = fmaf(e0, h0.x, a4.x); a4.y = fmaf(e0, h0.y, a4.y);
        a4.z = fmaf(e0, h0.z, a4.z); a4.w = fmaf(e0, h0.w, a4.w);
    }

    // combine even/odd halves (lane l and l+32 hold the same features/head)
    a4.x += __shfl_xor(a4.x, 32);
    a4.y += __shfl_xor(a4.y, 32);
    a4.z += __shfl_xor(a4.z, 32);
    a4.w += __shfl_xor(a4.w, 32);
    den  += __shfl_xor(den, 32);

    if (half == 0) {
        float rd = 1.f / fmaxf(den, 1e-16f);
        float4 bv = *(const float4*)(b + f);
        float x0 = a4.x * rd + bv.x;
        float x1 = a4.y * rd + bv.y;
        float x2 = a4.z * rd + bv.z;
        float x3 = a4.w * rd + bv.w;
        x0 = (x0 > 0.f) ? x0 : expm1f(x0);
        x1 = (x1 > 0.f) ? x1 : expm1f(x1);
        x2 = (x2 > 0.f) ? x2 : expm1f(x2);
        x3 = (x3 > 0.f) ? x3 : expm1f(x3);
        *(float4*)(out + (size_t)node * 128 + f) = make_float4(x0, x1, x2, x3);
    }
}

extern "C" void kernel_launch(void* const* d_in, const int* in_sizes, int n_in,
                              void* d_out, int out_size, void* d_ws, size_t ws_size,
                              hipStream_t stream) {
    const float* X    = (const float*)d_in[0];
    const int*   ei   = (const int*)d_in[1];
    const float* W0   = (const float*)d_in[2];
    const float* as0  = (const float*)d_in[3];
    const float* ad0  = (const float*)d_in[4];
    const float* b0   = (const float*)d_in[5];
    const float* W1   = (const float*)d_in[6];
    const float* as1  = (const float*)d_in[7];
    const float* ad1  = (const float*)d_in[8];
    const float* b1   = (const float*)d_in[9];

    const int* srcp = ei;            // edge_index[0]
    const int* dstp = ei + NEDGES;   // edge_index[1]

    float* ws = (float*)d_ws;
    float* h    = ws;                        // 6,400,000 floats
    float* hout = h    + 6400000;            // 6,400,000
    float* as_  = hout + 6400000;            // 200,000
    float* ad_  = as_  + 200000;             // 200,000
    int*   deg     = (int*)(ad_ + 200000);   // 50,000 ints
    int*   roff    = deg + 50000;            // 50,001
    int*   cursor  = roff + 50001;           // 50,000
    int*   csr_src = cursor + 50000;         // 800,000
    int*   bsum    = csr_src + 800000;       // 196
    int*   boff    = bsum + NSCANB;          // 196

    // ---- CSR build (by destination), layer-invariant ----
    hipMemsetAsync(deg, 0, NNODES * sizeof(int), stream);
    hist_kernel<<<(NEDGES + 255) / 256, 256, 0, stream>>>(dstp, deg);
    scan1_kernel<<<NSCANB, 256, 0, stream>>>(deg, bsum);
    scan2_kernel<<<1, 256, 0, stream>>>(bsum, boff, roff);
    scan3_kernel<<<NSCANB, 256, 0, stream>>>(deg, boff, roff, cursor);
    bucket_kernel<<<(NEDGES + 255) / 256, 256, 0, stream>>>(srcp, dstp, cursor, csr_src);

    const int NODE_BLOCKS = (NNODES + 3) / 4;   // 4 nodes (waves) per block

    for (int layer = 0; layer < 2; ++layer) {
        const float* Hin = layer ? hout : X;
        const float* W   = layer ? W1  : W0;
        const float* avs = layer ? as1 : as0;
        const float* avd = layer ? ad1 : ad0;
        const float* bv  = layer ? b1  : b0;
        float* outp      = layer ? (float*)d_out : hout;

        gemm_alpha_kernel<<<(NNODES + GBM - 1) / GBM, 256, 0, stream>>>(
            Hin, W, avs, avd, h, as_, ad_, NNODES);

        att_gather_kernel<<<NODE_BLOCKS, 256, 0, stream>>>(
            csr_src, roff, as_, ad_, h, bv, outp);
    }
}

// Round 10
// 238.640 us; speedup vs baseline: 2.0799x; 1.2006x over previous
//
#include <hip/hip_runtime.h>
#include <math.h>
#include <float.h>

#define NNODES 50000
#define NEDGES 800000
#define NSCANB ((NNODES + 255) / 256)   // 196
// feature dims: in=hid=out=128, heads=4, head_dim=32

typedef __attribute__((ext_vector_type(4))) _Float16 half4;
typedef __attribute__((ext_vector_type(8))) _Float16 half8;

// ---------------- CSR build ----------------
__global__ __launch_bounds__(256) void hist_kernel(const int* __restrict__ dst,
                                                   int* __restrict__ deg) {
    int e = blockIdx.x * 256 + threadIdx.x;
    if (e < NEDGES) atomicAdd(&deg[dst[e]], 1);
}

__global__ __launch_bounds__(256) void scan1_kernel(const int* __restrict__ deg,
                                                    int* __restrict__ bsum) {
    int i = blockIdx.x * 256 + threadIdx.x;
    int t = threadIdx.x, lane = t & 63, w = t >> 6;
    int v = (i < NNODES) ? deg[i] : 0;
    int x = v;
#pragma unroll
    for (int off = 1; off < 64; off <<= 1) x += __shfl_xor(x, off);
    __shared__ int wtot[4];
    if (lane == 0) wtot[w] = x;
    __syncthreads();
    if (t == 0) bsum[blockIdx.x] = wtot[0] + wtot[1] + wtot[2] + wtot[3];
}

__global__ __launch_bounds__(256) void scan2_kernel(const int* __restrict__ bsum,
                                                    int* __restrict__ boff,
                                                    int* __restrict__ roff) {
    __shared__ int s[256];
    int t = threadIdx.x;
    int v = (t < NSCANB) ? bsum[t] : 0;
    s[t] = v;
    __syncthreads();
    for (int off = 1; off < 256; off <<= 1) {
        int y = (t >= off) ? s[t - off] : 0;
        __syncthreads();
        s[t] += y;
        __syncthreads();
    }
    if (t < NSCANB) boff[t] = s[t] - v;
    if (t == 255) roff[NNODES] = s[255];
}

__global__ __launch_bounds__(256) void scan3_kernel(const int* __restrict__ deg,
                                                    const int* __restrict__ boff,
                                                    int* __restrict__ roff,
                                                    int* __restrict__ cursor) {
    int i = blockIdx.x * 256 + threadIdx.x;
    int t = threadIdx.x, lane = t & 63, w = t >> 6;
    int v = (i < NNODES) ? deg[i] : 0;
    int x = v;
#pragma unroll
    for (int off = 1; off < 64; off <<= 1) {
        int y = __shfl_up(x, off, 64);
        if (lane >= off) x += y;
    }
    __shared__ int wtot[4];
    if (lane == 63) wtot[w] = x;
    __syncthreads();
    int wpre = 0;
#pragma unroll
    for (int j = 0; j < 4; ++j) if (j < w) wpre += wtot[j];
    int ex = boff[blockIdx.x] + wpre + x - v;
    if (i < NNODES) { roff[i] = ex; cursor[i] = ex; }
}

__global__ __launch_bounds__(256) void bucket_kernel(const int* __restrict__ src,
                                                     const int* __restrict__ dst,
                                                     int* __restrict__ cursor,
                                                     int* __restrict__ csr_src) {
    int e = blockIdx.x * 256 + threadIdx.x;
    if (e >= NEDGES) return;
    int d = dst[e];
    int pos = atomicAdd(&cursor[d], 1);
    csr_src[pos] = src[e];
}

// ---------------- GEMM + alpha: h = X@W ; alpha_s/d = <h, a_src/dst> -------
// 128-row tile, 256 threads, 8x8 acc per thread. h stored as fp16 (read only
// by the gather; alphas + accumulation stay fp32; error bound ~3e-3 << 1.1e-2
// threshold since the output is a convex combination of h values).
#define GBM 128
#define GBK 32
__global__ __launch_bounds__(256) void gemm_alpha_kernel(
    const float* __restrict__ X, const float* __restrict__ W,
    const float* __restrict__ avs, const float* __restrict__ avd,
    _Float16* __restrict__ Hh, float* __restrict__ alpha_s, float* __restrict__ alpha_d,
    int nrows)
{
    __shared__ float Xs[GBK][GBM];   // transposed X tile: Xs[k][row], 16KB
    __shared__ float Ws[GBK][128];   // W tile: Ws[k][col], 16KB

    int t = threadIdx.x;
    int row0 = (t >> 4) * 8;         // 0..120
    int col0 = (t & 15) * 8;         // 0..120
    int block_row = blockIdx.x * GBM;

    float acc[8][8];
#pragma unroll
    for (int i = 0; i < 8; ++i)
#pragma unroll
        for (int j = 0; j < 8; ++j) acc[i][j] = 0.f;

    for (int k0 = 0; k0 < 128; k0 += GBK) {
        {
            int r  = t >> 1;               // 0..127
            int kb = (t & 1) * 16;         // 0 or 16
            int grow = block_row + r;
            float4 v0 = make_float4(0,0,0,0), v1 = v0, v2 = v0, v3 = v0;
            if (grow < nrows) {
                const float* p = X + (size_t)grow * 128 + k0 + kb;
                v0 = ((const float4*)p)[0];
                v1 = ((const float4*)p)[1];
                v2 = ((const float4*)p)[2];
                v3 = ((const float4*)p)[3];
            }
            Xs[kb+ 0][r] = v0.x; Xs[kb+ 1][r] = v0.y; Xs[kb+ 2][r] = v0.z; Xs[kb+ 3][r] = v0.w;
            Xs[kb+ 4][r] = v1.x; Xs[kb+ 5][r] = v1.y; Xs[kb+ 6][r] = v1.z; Xs[kb+ 7][r] = v1.w;
            Xs[kb+ 8][r] = v2.x; Xs[kb+ 9][r] = v2.y; Xs[kb+10][r] = v2.z; Xs[kb+11][r] = v2.w;
            Xs[kb+12][r] = v3.x; Xs[kb+13][r] = v3.y; Xs[kb+14][r] = v3.z; Xs[kb+15][r] = v3.w;
        }
        {
            int kr = t >> 3;               // 0..31
            int cc = (t & 7) * 16;         // 0..112
            const float* p = W + (size_t)(k0 + kr) * 128 + cc;
            float4 w0 = ((const float4*)p)[0];
            float4 w1 = ((const float4*)p)[1];
            float4 w2 = ((const float4*)p)[2];
            float4 w3 = ((const float4*)p)[3];
            *(float4*)&Ws[kr][cc + 0]  = w0;
            *(float4*)&Ws[kr][cc + 4]  = w1;
            *(float4*)&Ws[kr][cc + 8]  = w2;
            *(float4*)&Ws[kr][cc + 12] = w3;
        }
        __syncthreads();
#pragma unroll
        for (int kk = 0; kk < GBK; ++kk) {
            float4 a0 = *(const float4*)&Xs[kk][row0];
            float4 a1 = *(const float4*)&Xs[kk][row0 + 4];
            float4 w0 = *(const float4*)&Ws[kk][col0];
            float4 w1 = *(const float4*)&Ws[kk][col0 + 4];
            float av[8] = {a0.x, a0.y, a0.z, a0.w, a1.x, a1.y, a1.z, a1.w};
            float wv[8] = {w0.x, w0.y, w0.z, w0.w, w1.x, w1.y, w1.z, w1.w};
#pragma unroll
            for (int i = 0; i < 8; ++i)
#pragma unroll
                for (int j = 0; j < 8; ++j)
                    acc[i][j] = fmaf(av[i], wv[j], acc[i][j]);
        }
        __syncthreads();
    }

    int cg = t & 15;
    int head = cg >> 2;                       // col0/32
    const float* asrc = avs + head * 32 + (cg & 3) * 8;
    const float* adst = avd + head * 32 + (cg & 3) * 8;
#pragma unroll
    for (int i = 0; i < 8; ++i) {
        int grow = block_row + row0 + i;
        bool ok = (grow < nrows);
        if (ok) {
            half8 hv;
#pragma unroll
            for (int j = 0; j < 8; ++j) hv[j] = (_Float16)acc[i][j];
            *(half8*)&Hh[(size_t)grow * 128 + col0] = hv;   // 16B store
        }
        float ps = 0.f, pd = 0.f;
#pragma unroll
        for (int j = 0; j < 8; ++j) {
            ps = fmaf(acc[i][j], asrc[j], ps);
            pd = fmaf(acc[i][j], adst[j], pd);
        }
        ps += __shfl_xor(ps, 1); ps += __shfl_xor(ps, 2);
        pd += __shfl_xor(pd, 1); pd += __shfl_xor(pd, 2);
        if (ok && (cg & 3) == 0) {
            alpha_s[grow * 4 + head] = ps;
            alpha_d[grow * 4 + head] = pd;
        }
    }
}

// ------- fused attention + gather, SINGLE PASS, no LDS, fp16 h ------------
// out = elu( (sum_e ex_e * h[src_e]) / (sum_e ex_e) + b ),
// ex_e = exp(leakyrelu(alpha_s[src_e] + alpha_d[node]))  (no max-shift:
// logits are O(+-6), exp fp32-safe, softmax shift-invariant).
// One wave per node. half = lane>>5 handles edges of parity `half`; lane owns
// features q*4..q*4+3 (q = lane&31): 32 lanes x 8B = full 256B fp16 h row per
// edge. 4 independent edges per half-wave iteration. den accumulated
// alongside; both halves combined with one shfl_xor(32); normalize at end.
__global__ __launch_bounds__(256) void att_gather_kernel(
    const int* __restrict__ csr_src, const int* __restrict__ roff,
    const float* __restrict__ alpha_s, const float* __restrict__ alpha_d,
    const _Float16* __restrict__ hbuf, const float* __restrict__ b,
    float* __restrict__ out)
{
    int node = blockIdx.x * 4 + (threadIdx.x >> 6);
    if (node >= NNODES) return;
    int lane = threadIdx.x & 63;
    int half = lane >> 5;               // edge parity this lane handles
    int q    = lane & 31;
    int f    = q * 4;                   // features f..f+3
    int hh   = q >> 3;                  // head owning features f..f+3
    int beg = roff[node], end = roff[node + 1];
    float ad = alpha_d[node * 4 + hh];

    float4 a4 = make_float4(0.f, 0.f, 0.f, 0.f);
    float den = 0.f;
    int i = beg + half;
    for (; i + 6 < end; i += 8) {       // 4 independent edges per lane/iter
        int s0 = csr_src[i];
        int s1 = csr_src[i + 2];
        int s2 = csr_src[i + 4];
        int s3 = csr_src[i + 6];
        float l0 = alpha_s[s0 * 4 + hh] + ad;
        float l1 = alpha_s[s1 * 4 + hh] + ad;
        float l2 = alpha_s[s2 * 4 + hh] + ad;
        float l3 = alpha_s[s3 * 4 + hh] + ad;
        half4 h0 = *(const half4*)(hbuf + (size_t)s0 * 128 + f);
        half4 h1 = *(const half4*)(hbuf + (size_t)s1 * 128 + f);
        half4 h2 = *(const half4*)(hbuf + (size_t)s2 * 128 + f);
        half4 h3 = *(const half4*)(hbuf + (size_t)s3 * 128 + f);
        l0 = (l0 >= 0.f) ? l0 : 0.2f * l0;
        l1 = (l1 >= 0.f) ? l1 : 0.2f * l1;
        l2 = (l2 >= 0.f) ? l2 : 0.2f * l2;
        l3 = (l3 >= 0.f) ? l3 : 0.2f * l3;
        float e0 = __expf(l0);
        float e1 = __expf(l1);
        float e2 = __expf(l2);
        float e3 = __expf(l3);
        den += (e0 + e1) + (e2 + e3);
        a4.x = fmaf(e0, (float)h0[0], a4.x); a4.y = fmaf(e0, (float)h0[1], a4.y);
        a4.z = fmaf(e0, (float)h0[2], a4.z); a4.w = fmaf(e0, (float)h0[3], a4.w);
        a4.x = fmaf(e1, (float)h1[0], a4.x); a4.y = fmaf(e1, (float)h1[1], a4.y);
        a4.z = fmaf(e1, (float)h1[2], a4.z); a4.w = fmaf(e1, (float)h1[3], a4.w);
        a4.x = fmaf(e2, (float)h2[0], a4.x); a4.y = fmaf(e2, (float)h2[1], a4.y);
        a4.z = fmaf(e2, (float)h2[2], a4.z); a4.w = fmaf(e2, (float)h2[3], a4.w);
        a4.x = fmaf(e3, (float)h3[0], a4.x); a4.y = fmaf(e3, (float)h3[1], a4.y);
        a4.z = fmaf(e3, (float)h3[2], a4.z); a4.w = fmaf(e3, (float)h3[3], a4.w);
    }
    for (; i < end; i += 2) {           // tail: 0..3 edges of this parity
        int s0 = csr_src[i];
        float l0 = alpha_s[s0 * 4 + hh] + ad;
        l0 = (l0 >= 0.f) ? l0 : 0.2f * l0;
        float e0 = __expf(l0);
        half4 h0 = *(const half4*)(hbuf + (size_t)s0 * 128 + f);
        den += e0;
        a4.x = fmaf(e0, (float)h0[0], a4.x); a4.y = fmaf(e0, (float)h0[1], a4.y);
        a4.z = fmaf(e0, (float)h0[2], a4.z); a4.w = fmaf(e0, (float)h0[3], a4.w);
    }

    // combine even/odd halves (lane l and l+32 hold the same features/head)
    a4.x += __shfl_xor(a4.x, 32);
    a4.y += __shfl_xor(a4.y, 32);
    a4.z += __shfl_xor(a4.z, 32);
    a4.w += __shfl_xor(a4.w, 32);
    den  += __shfl_xor(den, 32);

    if (half == 0) {
        float rd = 1.f / fmaxf(den, 1e-16f);
        float4 bv = *(const float4*)(b + f);
        float x0 = a4.x * rd + bv.x;
        float x1 = a4.y * rd + bv.y;
        float x2 = a4.z * rd + bv.z;
        float x3 = a4.w * rd + bv.w;
        x0 = (x0 > 0.f) ? x0 : expm1f(x0);
        x1 = (x1 > 0.f) ? x1 : expm1f(x1);
        x2 = (x2 > 0.f) ? x2 : expm1f(x2);
        x3 = (x3 > 0.f) ? x3 : expm1f(x3);
        *(float4*)(out + (size_t)node * 128 + f) = make_float4(x0, x1, x2, x3);
    }
}

extern "C" void kernel_launch(void* const* d_in, const int* in_sizes, int n_in,
                              void* d_out, int out_size, void* d_ws, size_t ws_size,
                              hipStream_t stream) {
    const float* X    = (const float*)d_in[0];
    const int*   ei   = (const int*)d_in[1];
    const float* W0   = (const float*)d_in[2];
    const float* as0  = (const float*)d_in[3];
    const float* ad0  = (const float*)d_in[4];
    const float* b0   = (const float*)d_in[5];
    const float* W1   = (const float*)d_in[6];
    const float* as1  = (const float*)d_in[7];
    const float* ad1  = (const float*)d_in[8];
    const float* b1   = (const float*)d_in[9];

    const int* srcp = ei;            // edge_index[0]
    const int* dstp = ei + NEDGES;   // edge_index[1]

    float* ws = (float*)d_ws;
    _Float16* h16 = (_Float16*)ws;           // 6,400,000 halves (3.2M floats)
    float* hout = ws + 3200000;              // 6,400,000 floats
    float* as_  = hout + 6400000;            // 200,000
    float* ad_  = as_  + 200000;             // 200,000
    int*   deg     = (int*)(ad_ + 200000);   // 50,000 ints
    int*   roff    = deg + 50000;            // 50,001
    int*   cursor  = roff + 50001;           // 50,000
    int*   csr_src = cursor + 50000;         // 800,000
    int*   bsum    = csr_src + 800000;       // 196
    int*   boff    = bsum + NSCANB;          // 196

    // ---- CSR build (by destination), layer-invariant ----
    hipMemsetAsync(deg, 0, NNODES * sizeof(int), stream);
    hist_kernel<<<(NEDGES + 255) / 256, 256, 0, stream>>>(dstp, deg);
    scan1_kernel<<<NSCANB, 256, 0, stream>>>(deg, bsum);
    scan2_kernel<<<1, 256, 0, stream>>>(bsum, boff, roff);
    scan3_kernel<<<NSCANB, 256, 0, stream>>>(deg, boff, roff, cursor);
    bucket_kernel<<<(NEDGES + 255) / 256, 256, 0, stream>>>(srcp, dstp, cursor, csr_src);

    const int NODE_BLOCKS = (NNODES + 3) / 4;   // 4 nodes (waves) per block

    for (int layer = 0; layer < 2; ++layer) {
        const float* Hin = layer ? hout : X;
        const float* W   = layer ? W1  : W0;
        const float* avs = layer ? as1 : as0;
        const float* avd = layer ? ad1 : ad0;
        const float* bv  = layer ? b1  : b0;
        float* outp      = layer ? (float*)d_out : hout;

        gemm_alpha_kernel<<<(NNODES + GBM - 1) / GBM, 256, 0, stream>>>(
            Hin, W, avs, avd, h16, as_, ad_, NNODES);

        att_gather_kernel<<<NODE_BLOCKS, 256, 0, stream>>>(
            csr_src, roff, as_, ad_, h16, bv, outp);
    }
}

// Round 11
// 173.213 us; speedup vs baseline: 2.8656x; 1.3777x over previous
//
#include <hip/hip_runtime.h>
#include <math.h>
#include <float.h>

#define NNODES 50000
#define NEDGES 800000
// feature dims: in=hid=out=128, heads=4, head_dim=32

// ---- CSR binning params ----
#define KB    196                       // coarse bins (dst>>8), covers 50176 nodes
#define NPB   256                       // nodes per bin
#define CAPB  4608                      // per-bin capacity (mean 4081, +8 sigma)
#define EPB   4096                      // edges per pass-A block
#define NABLK ((NEDGES + EPB - 1) / EPB)   // 196

typedef __attribute__((ext_vector_type(4))) _Float16 half4;
typedef __attribute__((ext_vector_type(8))) _Float16 half8;

// ---------------- CSR build, two-pass LDS binning ----------------
__global__ __launch_bounds__(256) void bininit_kernel(int* __restrict__ bincur) {
    int t = threadIdx.x;
    if (t < KB) bincur[t] = t * CAPB;
}

// Pass A: stage 4096 edges in LDS grouped by coarse bin (dst>>8), then write
// each bin's run contiguously into the bin's global region (one atomicAdd per
// (block,bin) reserves the run). Converts 800K random 4B scatter writes into
// ~38K contiguous bursts -> kills the 16x HBM write amplification.
__global__ __launch_bounds__(256) void binA_kernel(
    const int* __restrict__ src, const int* __restrict__ dst,
    int* __restrict__ bincur, unsigned* __restrict__ binned)
{
    __shared__ int lhist[KB];
    __shared__ int lstart[KB];
    __shared__ int lcur[KB];
    __shared__ int gbase[KB];
    __shared__ unsigned lbuf[EPB];
    __shared__ int wtot[4];

    int t = threadIdx.x;
    int e0 = blockIdx.x * EPB;
    int ecnt = NEDGES - e0; if (ecnt > EPB) ecnt = EPB;

    for (int b = t; b < KB; b += 256) lhist[b] = 0;
    __syncthreads();

    // count
    for (int idx = t; idx < ecnt; idx += 256)
        atomicAdd(&lhist[((unsigned)dst[e0 + idx]) >> 8], 1);
    __syncthreads();

    // exclusive scan of lhist[0..KB) across 256 threads
    {
        int lane = t & 63, w = t >> 6;
        int v = (t < KB) ? lhist[t] : 0;
        int x = v;
#pragma unroll
        for (int off = 1; off < 64; off <<= 1) {
            int y = __shfl_up(x, off, 64);
            if (lane >= off) x += y;
        }
        if (lane == 63) wtot[w] = x;
        __syncthreads();
        int wpre = 0;
#pragma unroll
        for (int j = 0; j < 4; ++j) if (j < w) wpre += wtot[j];
        int ex = wpre + x - v;
        if (t < KB) { lstart[t] = ex; lcur[t] = ex; }
    }
    __syncthreads();

    // reserve global runs (one atomic per bin with nonzero count)
    if (t < KB) {
        int c = lhist[t];
        gbase[t] = c ? atomicAdd(&bincur[t], c) : 0;
    }
    __syncthreads();

    // place into LDS grouped by bin
    for (int idx = t; idx < ecnt; idx += 256) {
        unsigned d = (unsigned)dst[e0 + idx];
        unsigned s = (unsigned)src[e0 + idx];
        int pos = atomicAdd(&lcur[d >> 8], 1);
        lbuf[pos] = (d << 16) | s;
    }
    __syncthreads();

    // copy out: contiguous per-bin runs
    for (int idx = t; idx < ecnt; idx += 256) {
        unsigned p = lbuf[idx];
        int b = p >> 24;                       // dst>>8
        binned[gbase[b] + (idx - lstart[b])] = p;
    }
}

// Pass B: block k owns bin k (nodes k*256..k*256+255). Local hist+scan, then
// scatter into the final CAP-padded csr region owned by THIS block only (one
// XCD -> full-line writebacks). Emits node_info = (beg, deg) per node.
__global__ __launch_bounds__(256) void binB_kernel(
    const unsigned* __restrict__ binned, const int* __restrict__ bincur,
    int* __restrict__ csr_src, int2* __restrict__ node_info)
{
    __shared__ int lhist[NPB];
    __shared__ int lcur[NPB];
    __shared__ int wtot[4];
    int k = blockIdx.x;
    int t = threadIdx.x;
    int base = k * CAPB;
    int cnt = bincur[k] - base;

    lhist[t] = 0;
    __syncthreads();

    for (int i = t; i < cnt; i += 256)
        atomicAdd(&lhist[(binned[base + i] >> 16) & 0xFF], 1);
    __syncthreads();

    // exclusive scan of 256 counters
    int lane = t & 63, w = t >> 6;
    int v = lhist[t];
    int x = v;
#pragma unroll
    for (int off = 1; off < 64; off <<= 1) {
        int y = __shfl_up(x, off, 64);
        if (lane >= off) x += y;
    }
    if (lane == 63) wtot[w] = x;
    __syncthreads();
    int wpre = 0;
#pragma unroll
    for (int j = 0; j < 4; ++j) if (j < w) wpre += wtot[j];
    int ex = wpre + x - v;
    lcur[t] = ex;
    int node = k * NPB + t;
    if (node < NNODES) node_info[node] = make_int2(base + ex, v);
    __syncthreads();

    // scatter within this block's private region
    for (int i = t; i < cnt; i += 256) {
        unsigned p = binned[base + i];
        int ln = (p >> 16) & 0xFF;
        int pos = atomicAdd(&lcur[ln], 1);
        csr_src[base + pos] = (int)(p & 0xFFFFu);
    }
}

// ---------------- GEMM + alpha: h = X@W ; alpha_s/d = <h, a_src/dst> -------
// 128-row tile, 256 threads, 8x8 acc per thread. h stored as fp16 (read only
// by the gather; alphas + accumulation stay fp32).
#define GBM 128
#define GBK 32
__global__ __launch_bounds__(256) void gemm_alpha_kernel(
    const float* __restrict__ X, const float* __restrict__ W,
    const float* __restrict__ avs, const float* __restrict__ avd,
    _Float16* __restrict__ Hh, float* __restrict__ alpha_s, float* __restrict__ alpha_d,
    int nrows)
{
    __shared__ float Xs[GBK][GBM];
    __shared__ float Ws[GBK][128];

    int t = threadIdx.x;
    int row0 = (t >> 4) * 8;
    int col0 = (t & 15) * 8;
    int block_row = blockIdx.x * GBM;

    float acc[8][8];
#pragma unroll
    for (int i = 0; i < 8; ++i)
#pragma unroll
        for (int j = 0; j < 8; ++j) acc[i][j] = 0.f;

    for (int k0 = 0; k0 < 128; k0 += GBK) {
        {
            int r  = t >> 1;
            int kb = (t & 1) * 16;
            int grow = block_row + r;
            float4 v0 = make_float4(0,0,0,0), v1 = v0, v2 = v0, v3 = v0;
            if (grow < nrows) {
                const float* p = X + (size_t)grow * 128 + k0 + kb;
                v0 = ((const float4*)p)[0];
                v1 = ((const float4*)p)[1];
                v2 = ((const float4*)p)[2];
                v3 = ((const float4*)p)[3];
            }
            Xs[kb+ 0][r] = v0.x; Xs[kb+ 1][r] = v0.y; Xs[kb+ 2][r] = v0.z; Xs[kb+ 3][r] = v0.w;
            Xs[kb+ 4][r] = v1.x; Xs[kb+ 5][r] = v1.y; Xs[kb+ 6][r] = v1.z; Xs[kb+ 7][r] = v1.w;
            Xs[kb+ 8][r] = v2.x; Xs[kb+ 9][r] = v2.y; Xs[kb+10][r] = v2.z; Xs[kb+11][r] = v2.w;
            Xs[kb+12][r] = v3.x; Xs[kb+13][r] = v3.y; Xs[kb+14][r] = v3.z; Xs[kb+15][r] = v3.w;
        }
        {
            int kr = t >> 3;
            int cc = (t & 7) * 16;
            const float* p = W + (size_t)(k0 + kr) * 128 + cc;
            float4 w0 = ((const float4*)p)[0];
            float4 w1 = ((const float4*)p)[1];
            float4 w2 = ((const float4*)p)[2];
            float4 w3 = ((const float4*)p)[3];
            *(float4*)&Ws[kr][cc + 0]  = w0;
            *(float4*)&Ws[kr][cc + 4]  = w1;
            *(float4*)&Ws[kr][cc + 8]  = w2;
            *(float4*)&Ws[kr][cc + 12] = w3;
        }
        __syncthreads();
#pragma unroll
        for (int kk = 0; kk < GBK; ++kk) {
            float4 a0 = *(const float4*)&Xs[kk][row0];
            float4 a1 = *(const float4*)&Xs[kk][row0 + 4];
            float4 w0 = *(const float4*)&Ws[kk][col0];
            float4 w1 = *(const float4*)&Ws[kk][col0 + 4];
            float av[8] = {a0.x, a0.y, a0.z, a0.w, a1.x, a1.y, a1.z, a1.w};
            float wv[8] = {w0.x, w0.y, w0.z, w0.w, w1.x, w1.y, w1.z, w1.w};
#pragma unroll
            for (int i = 0; i < 8; ++i)
#pragma unroll
                for (int j = 0; j < 8; ++j)
                    acc[i][j] = fmaf(av[i], wv[j], acc[i][j]);
        }
        __syncthreads();
    }

    int cg = t & 15;
    int head = cg >> 2;
    const float* asrc = avs + head * 32 + (cg & 3) * 8;
    const float* adst = avd + head * 32 + (cg & 3) * 8;
#pragma unroll
    for (int i = 0; i < 8; ++i) {
        int grow = block_row + row0 + i;
        bool ok = (grow < nrows);
        if (ok) {
            half8 hv;
#pragma unroll
            for (int j = 0; j < 8; ++j) hv[j] = (_Float16)acc[i][j];
            *(half8*)&Hh[(size_t)grow * 128 + col0] = hv;   // 16B store
        }
        float ps = 0.f, pd = 0.f;
#pragma unroll
        for (int j = 0; j < 8; ++j) {
            ps = fmaf(acc[i][j], asrc[j], ps);
            pd = fmaf(acc[i][j], adst[j], pd);
        }
        ps += __shfl_xor(ps, 1); ps += __shfl_xor(ps, 2);
        pd += __shfl_xor(pd, 1); pd += __shfl_xor(pd, 2);
        if (ok && (cg & 3) == 0) {
            alpha_s[grow * 4 + head] = ps;
            alpha_d[grow * 4 + head] = pd;
        }
    }
}

// ------- fused attention + gather, SINGLE PASS, no LDS, fp16 h ------------
__global__ __launch_bounds__(256) void att_gather_kernel(
    const int* __restrict__ csr_src, const int2* __restrict__ node_info,
    const float* __restrict__ alpha_s, const float* __restrict__ alpha_d,
    const _Float16* __restrict__ hbuf, const float* __restrict__ b,
    float* __restrict__ out)
{
    int node = blockIdx.x * 4 + (threadIdx.x >> 6);
    if (node >= NNODES) return;
    int lane = threadIdx.x & 63;
    int half = lane >> 5;               // edge parity this lane handles
    int q    = lane & 31;
    int f    = q * 4;                   // features f..f+3
    int hh   = q >> 3;                  // head owning features f..f+3
    int2 bi = node_info[node];
    int beg = bi.x, end = bi.x + bi.y;
    float ad = alpha_d[node * 4 + hh];

    float4 a4 = make_float4(0.f, 0.f, 0.f, 0.f);
    float den = 0.f;
    int i = beg + half;
    for (; i + 6 < end; i += 8) {       // 4 independent edges per lane/iter
        int s0 = csr_src[i];
        int s1 = csr_src[i + 2];
        int s2 = csr_src[i + 4];
        int s3 = csr_src[i + 6];
        float l0 = alpha_s[s0 * 4 + hh] + ad;
        float l1 = alpha_s[s1 * 4 + hh] + ad;
        float l2 = alpha_s[s2 * 4 + hh] + ad;
        float l3 = alpha_s[s3 * 4 + hh] + ad;
        half4 h0 = *(const half4*)(hbuf + (size_t)s0 * 128 + f);
        half4 h1 = *(const half4*)(hbuf + (size_t)s1 * 128 + f);
        half4 h2 = *(const half4*)(hbuf + (size_t)s2 * 128 + f);
        half4 h3 = *(const half4*)(hbuf + (size_t)s3 * 128 + f);
        l0 = (l0 >= 0.f) ? l0 : 0.2f * l0;
        l1 = (l1 >= 0.f) ? l1 : 0.2f * l1;
        l2 = (l2 >= 0.f) ? l2 : 0.2f * l2;
        l3 = (l3 >= 0.f) ? l3 : 0.2f * l3;
        float e0 = __expf(l0);
        float e1 = __expf(l1);
        float e2 = __expf(l2);
        float e3 = __expf(l3);
        den += (e0 + e1) + (e2 + e3);
        a4.x = fmaf(e0, (float)h0[0], a4.x); a4.y = fmaf(e0, (float)h0[1], a4.y);
        a4.z = fmaf(e0, (float)h0[2], a4.z); a4.w = fmaf(e0, (float)h0[3], a4.w);
        a4.x = fmaf(e1, (float)h1[0], a4.x); a4.y = fmaf(e1, (float)h1[1], a4.y);
        a4.z = fmaf(e1, (float)h1[2], a4.z); a4.w = fmaf(e1, (float)h1[3], a4.w);
        a4.x = fmaf(e2, (float)h2[0], a4.x); a4.y = fmaf(e2, (float)h2[1], a4.y);
        a4.z = fmaf(e2, (float)h2[2], a4.z); a4.w = fmaf(e2, (float)h2[3], a4.w);
        a4.x = fmaf(e3, (float)h3[0], a4.x); a4.y = fmaf(e3, (float)h3[1], a4.y);
        a4.z = fmaf(e3, (float)h3[2], a4.z); a4.w = fmaf(e3, (float)h3[3], a4.w);
    }
    for (; i < end; i += 2) {           // tail: 0..3 edges of this parity
        int s0 = csr_src[i];
        float l0 = alpha_s[s0 * 4 + hh] + ad;
        l0 = (l0 >= 0.f) ? l0 : 0.2f * l0;
        float e0 = __expf(l0);
        half4 h0 = *(const half4*)(hbuf + (size_t)s0 * 128 + f);
        den += e0;
        a4.x = fmaf(e0, (float)h0[0], a4.x); a4.y = fmaf(e0, (float)h0[1], a4.y);
        a4.z = fmaf(e0, (float)h0[2], a4.z); a4.w = fmaf(e0, (float)h0[3], a4.w);
    }

    // combine even/odd halves (lane l and l+32 hold the same features/head)
    a4.x += __shfl_xor(a4.x, 32);
    a4.y += __shfl_xor(a4.y, 32);
    a4.z += __shfl_xor(a4.z, 32);
    a4.w += __shfl_xor(a4.w, 32);
    den  += __shfl_xor(den, 32);

    if (half == 0) {
        float rd = 1.f / fmaxf(den, 1e-16f);
        float4 bv = *(const float4*)(b + f);
        float x0 = a4.x * rd + bv.x;
        float x1 = a4.y * rd + bv.y;
        float x2 = a4.z * rd + bv.z;
        float x3 = a4.w * rd + bv.w;
        x0 = (x0 > 0.f) ? x0 : expm1f(x0);
        x1 = (x1 > 0.f) ? x1 : expm1f(x1);
        x2 = (x2 > 0.f) ? x2 : expm1f(x2);
        x3 = (x3 > 0.f) ? x3 : expm1f(x3);
        *(float4*)(out + (size_t)node * 128 + f) = make_float4(x0, x1, x2, x3);
    }
}

extern "C" void kernel_launch(void* const* d_in, const int* in_sizes, int n_in,
                              void* d_out, int out_size, void* d_ws, size_t ws_size,
                              hipStream_t stream) {
    const float* X    = (const float*)d_in[0];
    const int*   ei   = (const int*)d_in[1];
    const float* W0   = (const float*)d_in[2];
    const float* as0  = (const float*)d_in[3];
    const float* ad0  = (const float*)d_in[4];
    const float* b0   = (const float*)d_in[5];
    const float* W1   = (const float*)d_in[6];
    const float* as1  = (const float*)d_in[7];
    const float* ad1  = (const float*)d_in[8];
    const float* b1   = (const float*)d_in[9];

    const int* srcp = ei;            // edge_index[0]
    const int* dstp = ei + NEDGES;   // edge_index[1]

    float* ws = (float*)d_ws;
    _Float16* h16 = (_Float16*)ws;             // 6.4M halves (3.2M floats)
    float* hout = ws + 3200000;                // 6.4M floats
    float* as_  = hout + 6400000;              // 200,000
    float* ad_  = as_  + 200000;               // 200,000
    unsigned* binned = (unsigned*)(ad_ + 200000);  // (KB+1)*CAPB (pad 1 bin)
    int*  csr_src   = (int*)(binned + (KB + 1) * CAPB);   // KB*CAPB
    int2* node_info = (int2*)(csr_src + KB * CAPB);       // 50,000 int2
    int*  bincur    = (int*)(node_info + NNODES);         // KB

    // ---- CSR build (two-pass LDS binning), layer-invariant ----
    bininit_kernel<<<1, 256, 0, stream>>>(bincur);
    binA_kernel<<<NABLK, 256, 0, stream>>>(srcp, dstp, bincur, binned);
    binB_kernel<<<KB, 256, 0, stream>>>(binned, bincur, csr_src, node_info);

    const int NODE_BLOCKS = (NNODES + 3) / 4;   // 4 nodes (waves) per block

    for (int layer = 0; layer < 2; ++layer) {
        const float* Hin = layer ? hout : X;
        const float* W   = layer ? W1  : W0;
        const float* avs = layer ? as1 : as0;
        const float* avd = layer ? ad1 : ad0;
        const float* bv  = layer ? b1  : b0;
        float* outp      = layer ? (float*)d_out : hout;

        gemm_alpha_kernel<<<(NNODES + GBM - 1) / GBM, 256, 0, stream>>>(
            Hin, W, avs, avd, h16, as_, ad_, NNODES);

        att_gather_kernel<<<NODE_BLOCKS, 256, 0, stream>>>(
            csr_src, node_info, as_, ad_, h16, bv, outp);
    }
}

// Round 12
// 160.203 us; speedup vs baseline: 3.0983x; 1.0812x over previous
//
#include <hip/hip_runtime.h>
#include <math.h>
#include <float.h>

#define NNODES 50000
#define NEDGES 800000
// feature dims: in=hid=out=128, heads=4, head_dim=32

// ---- CSR binning params ----
#define KB    196                       // coarse bins (dst>>8), covers 50176 nodes
#define NPB   256                       // nodes per bin
#define CAPB  4608                      // per-bin capacity (mean 4081, +8 sigma)
#define EPB   4096                      // edges per pass-A block
#define NABLK ((NEDGES + EPB - 1) / EPB)   // 196

typedef __attribute__((ext_vector_type(4))) _Float16 half4;
typedef __attribute__((ext_vector_type(8))) _Float16 half8;
typedef __attribute__((ext_vector_type(4))) float f32x4;

// ---------------- CSR build, two-pass LDS binning ----------------
__global__ __launch_bounds__(256) void bininit_kernel(int* __restrict__ bincur) {
    int t = threadIdx.x;
    if (t < KB) bincur[t] = t * CAPB;
}

__global__ __launch_bounds__(256) void binA_kernel(
    const int* __restrict__ src, const int* __restrict__ dst,
    int* __restrict__ bincur, unsigned* __restrict__ binned)
{
    __shared__ int lhist[KB];
    __shared__ int lstart[KB];
    __shared__ int lcur[KB];
    __shared__ int gbase[KB];
    __shared__ unsigned lbuf[EPB];
    __shared__ int wtot[4];

    int t = threadIdx.x;
    int e0 = blockIdx.x * EPB;
    int ecnt = NEDGES - e0; if (ecnt > EPB) ecnt = EPB;

    for (int b = t; b < KB; b += 256) lhist[b] = 0;
    __syncthreads();

    for (int idx = t; idx < ecnt; idx += 256)
        atomicAdd(&lhist[((unsigned)dst[e0 + idx]) >> 8], 1);
    __syncthreads();

    {
        int lane = t & 63, w = t >> 6;
        int v = (t < KB) ? lhist[t] : 0;
        int x = v;
#pragma unroll
        for (int off = 1; off < 64; off <<= 1) {
            int y = __shfl_up(x, off, 64);
            if (lane >= off) x += y;
        }
        if (lane == 63) wtot[w] = x;
        __syncthreads();
        int wpre = 0;
#pragma unroll
        for (int j = 0; j < 4; ++j) if (j < w) wpre += wtot[j];
        int ex = wpre + x - v;
        if (t < KB) { lstart[t] = ex; lcur[t] = ex; }
    }
    __syncthreads();

    if (t < KB) {
        int c = lhist[t];
        gbase[t] = c ? atomicAdd(&bincur[t], c) : 0;
    }
    __syncthreads();

    for (int idx = t; idx < ecnt; idx += 256) {
        unsigned d = (unsigned)dst[e0 + idx];
        unsigned s = (unsigned)src[e0 + idx];
        int pos = atomicAdd(&lcur[d >> 8], 1);
        lbuf[pos] = (d << 16) | s;
    }
    __syncthreads();

    for (int idx = t; idx < ecnt; idx += 256) {
        unsigned p = lbuf[idx];
        int b = p >> 24;
        binned[gbase[b] + (idx - lstart[b])] = p;
    }
}

__global__ __launch_bounds__(256) void binB_kernel(
    const unsigned* __restrict__ binned, const int* __restrict__ bincur,
    int* __restrict__ csr_src, int2* __restrict__ node_info)
{
    __shared__ int lhist[NPB];
    __shared__ int lcur[NPB];
    __shared__ int wtot[4];
    int k = blockIdx.x;
    int t = threadIdx.x;
    int base = k * CAPB;
    int cnt = bincur[k] - base;

    lhist[t] = 0;
    __syncthreads();

    for (int i = t; i < cnt; i += 256)
        atomicAdd(&lhist[(binned[base + i] >> 16) & 0xFF], 1);
    __syncthreads();

    int lane = t & 63, w = t >> 6;
    int v = lhist[t];
    int x = v;
#pragma unroll
    for (int off = 1; off < 64; off <<= 1) {
        int y = __shfl_up(x, off, 64);
        if (lane >= off) x += y;
    }
    if (lane == 63) wtot[w] = x;
    __syncthreads();
    int wpre = 0;
#pragma unroll
    for (int j = 0; j < 4; ++j) if (j < w) wpre += wtot[j];
    int ex = wpre + x - v;
    lcur[t] = ex;
    int node = k * NPB + t;
    if (node < NNODES) node_info[node] = make_int2(base + ex, v);
    __syncthreads();

    for (int i = t; i < cnt; i += 256) {
        unsigned p = binned[base + i];
        int ln = (p >> 16) & 0xFF;
        int pos = atomicAdd(&lcur[ln], 1);
        csr_src[base + pos] = (int)(p & 0xFFFFu);
    }
}

// ---------------- prep: X -> fp16, W0/W1 -> fp16 transposed [col][k] -------
__global__ __launch_bounds__(256) void prep_kernel(
    const float* __restrict__ X, const float* __restrict__ W0,
    const float* __restrict__ W1, _Float16* __restrict__ X16,
    _Float16* __restrict__ W0t, _Float16* __restrict__ W1t)
{
    int i = blockIdx.x * 256 + threadIdx.x;
    int stride = gridDim.x * 256;
    const int nx4 = NNODES * 128 / 4;
    for (int idx = i; idx < nx4; idx += stride) {
        float4 v = ((const float4*)X)[idx];
        half4 h = {(_Float16)v.x, (_Float16)v.y, (_Float16)v.z, (_Float16)v.w};
        ((half4*)X16)[idx] = h;
    }
    for (int idx = i; idx < 128 * 128; idx += stride) {
        int cc = idx >> 7, k = idx & 127;
        W0t[idx] = (_Float16)W0[k * 128 + cc];
        W1t[idx] = (_Float16)W1[k * 128 + cc];
    }
}

// ---------------- MFMA GEMM + alpha: h = A@W ; alpha_s/d = <h, a_*> -------
// A fp16 [nrows][128]; Wt fp16 [128 cols][128 k] (W transposed). Block =
// 256 thr = 4 waves; tile 64 rows x 128 cols; wave w owns rows w*16..+15.
// v_mfma_f32_16x16x32_f16: A-frag lane l = A[l&15][(l>>4)*8+j];
// B-frag lane l = B[(l>>4)*8+j][l&15] (8-contig in K from Wt rows);
// C/D lane l reg r = (row=(l>>4)*4+r, col=l&15) [guide-verified].
// LDS rows padded to 136 fp16 (272B) -> 2-way bank aliasing only (free).
#define GP 136
__global__ __launch_bounds__(256) void gemm_mfma_kernel(
    const _Float16* __restrict__ A, const _Float16* __restrict__ Wt,
    const float* __restrict__ avs, const float* __restrict__ avd,
    _Float16* __restrict__ Hh, float* __restrict__ alpha_s,
    float* __restrict__ alpha_d, int nrows)
{
    __shared__ _Float16 Xs[64 * GP];    // 17.0 KB
    __shared__ _Float16 Ws[128 * GP];   // 34.0 KB

    int t = threadIdx.x;
    int brow = blockIdx.x * 64;

    // stage A rows (64 x 256B): thread t -> row t>>2, 64B chunk t&3
    {
        int r = t >> 2, q = t & 3;
        int grow = brow + r;
        half8 v0 = {}, v1 = {}, v2 = {}, v3 = {};
        if (grow < nrows) {
            const half8* p = (const half8*)(A + (size_t)grow * 128 + q * 32);
            v0 = p[0]; v1 = p[1]; v2 = p[2]; v3 = p[3];
        }
        _Float16* d = Xs + r * GP + q * 32;
        *(half8*)(d + 0)  = v0; *(half8*)(d + 8)  = v1;
        *(half8*)(d + 16) = v2; *(half8*)(d + 24) = v3;
    }
    // stage Wt (128 x 256B = 32KB): thread t -> row t>>1, 128B half t&1
    {
        int wr = t >> 1, wh = t & 1;
        const half8* p = (const half8*)(Wt + wr * 128 + wh * 64);
        _Float16* d = Ws + wr * GP + wh * 64;
#pragma unroll
        for (int j = 0; j < 8; ++j) *(half8*)(d + j * 8) = p[j];
    }
    __syncthreads();

    int wv = t >> 6, l = t & 63;
    int lrow = l & 15;
    int lk8  = (l >> 4) * 8;

    f32x4 acc[8];
#pragma unroll
    for (int n = 0; n < 8; ++n) acc[n] = (f32x4){0.f, 0.f, 0.f, 0.f};

    const _Float16* xbase = Xs + (wv * 16 + lrow) * GP + lk8;
#pragma unroll
    for (int kk = 0; kk < 4; ++kk) {
        half8 a = *(const half8*)(xbase + kk * 32);
#pragma unroll
        for (int n = 0; n < 8; ++n) {
            half8 bf = *(const half8*)(Ws + (n * 16 + lrow) * GP + kk * 32 + lk8);
            acc[n] = __builtin_amdgcn_mfma_f32_16x16x32_f16(a, bf, acc[n], 0, 0, 0);
        }
    }

    // epilogue: h16 stores + fused alpha dot products
    int c = lrow;            // col within tile
    int g = l >> 4;          // row group (rows g*4..g*4+3)
#pragma unroll
    for (int n = 0; n < 8; ++n) {
#pragma unroll
        for (int r = 0; r < 4; ++r) {
            int row = brow + wv * 16 + g * 4 + r;
            if (row < nrows)
                Hh[(size_t)row * 128 + n * 16 + c] = (_Float16)acc[n][r];
        }
    }
#pragma unroll
    for (int hd = 0; hd < 4; ++hd) {
        float as0 = avs[hd * 32 + c], as1 = avs[hd * 32 + 16 + c];
        float ad0 = avd[hd * 32 + c], ad1 = avd[hd * 32 + 16 + c];
#pragma unroll
        for (int r = 0; r < 4; ++r) {
            float ps = acc[2 * hd][r] * as0 + acc[2 * hd + 1][r] * as1;
            float pd = acc[2 * hd][r] * ad0 + acc[2 * hd + 1][r] * ad1;
            ps += __shfl_xor(ps, 1); ps += __shfl_xor(ps, 2);
            ps += __shfl_xor(ps, 4); ps += __shfl_xor(ps, 8);
            pd += __shfl_xor(pd, 1); pd += __shfl_xor(pd, 2);
            pd += __shfl_xor(pd, 4); pd += __shfl_xor(pd, 8);
            if (c == 0) {
                int row = brow + wv * 16 + g * 4 + r;
                if (row < nrows) {
                    alpha_s[row * 4 + hd] = ps;
                    alpha_d[row * 4 + hd] = pd;
                }
            }
        }
    }
}

// ------- fused attention + gather, SINGLE PASS, no LDS, fp16 h ------------
template <bool F16OUT>
__global__ __launch_bounds__(256) void att_gather_kernel(
    const int* __restrict__ csr_src, const int2* __restrict__ node_info,
    const float* __restrict__ alpha_s, const float* __restrict__ alpha_d,
    const _Float16* __restrict__ hbuf, const float* __restrict__ b,
    float* __restrict__ out32, _Float16* __restrict__ out16)
{
    int node = blockIdx.x * 4 + (threadIdx.x >> 6);
    if (node >= NNODES) return;
    int lane = threadIdx.x & 63;
    int half = lane >> 5;               // edge parity this lane handles
    int q    = lane & 31;
    int f    = q * 4;                   // features f..f+3
    int hh   = q >> 3;                  // head owning features f..f+3
    int2 bi = node_info[node];
    int beg = bi.x, end = bi.x + bi.y;
    float ad = alpha_d[node * 4 + hh];

    float4 a4 = make_float4(0.f, 0.f, 0.f, 0.f);
    float den = 0.f;
    int i = beg + half;
    for (; i + 6 < end; i += 8) {       // 4 independent edges per lane/iter
        int s0 = csr_src[i];
        int s1 = csr_src[i + 2];
        int s2 = csr_src[i + 4];
        int s3 = csr_src[i + 6];
        float l0 = alpha_s[s0 * 4 + hh] + ad;
        float l1 = alpha_s[s1 * 4 + hh] + ad;
        float l2 = alpha_s[s2 * 4 + hh] + ad;
        float l3 = alpha_s[s3 * 4 + hh] + ad;
        half4 h0 = *(const half4*)(hbuf + (size_t)s0 * 128 + f);
        half4 h1 = *(const half4*)(hbuf + (size_t)s1 * 128 + f);
        half4 h2 = *(const half4*)(hbuf + (size_t)s2 * 128 + f);
        half4 h3 = *(const half4*)(hbuf + (size_t)s3 * 128 + f);
        l0 = (l0 >= 0.f) ? l0 : 0.2f * l0;
        l1 = (l1 >= 0.f) ? l1 : 0.2f * l1;
        l2 = (l2 >= 0.f) ? l2 : 0.2f * l2;
        l3 = (l3 >= 0.f) ? l3 : 0.2f * l3;
        float e0 = __expf(l0);
        float e1 = __expf(l1);
        float e2 = __expf(l2);
        float e3 = __expf(l3);
        den += (e0 + e1) + (e2 + e3);
        a4.x = fmaf(e0, (float)h0[0], a4.x); a4.y = fmaf(e0, (float)h0[1], a4.y);
        a4.z = fmaf(e0, (float)h0[2], a4.z); a4.w = fmaf(e0, (float)h0[3], a4.w);
        a4.x = fmaf(e1, (float)h1[0], a4.x); a4.y = fmaf(e1, (float)h1[1], a4.y);
        a4.z = fmaf(e1, (float)h1[2], a4.z); a4.w = fmaf(e1, (float)h1[3], a4.w);
        a4.x = fmaf(e2, (float)h2[0], a4.x); a4.y = fmaf(e2, (float)h2[1], a4.y);
        a4.z = fmaf(e2, (float)h2[2], a4.z); a4.w = fmaf(e2, (float)h2[3], a4.w);
        a4.x = fmaf(e3, (float)h3[0], a4.x); a4.y = fmaf(e3, (float)h3[1], a4.y);
        a4.z = fmaf(e3, (float)h3[2], a4.z); a4.w = fmaf(e3, (float)h3[3], a4.w);
    }
    for (; i < end; i += 2) {           // tail
        int s0 = csr_src[i];
        float l0 = alpha_s[s0 * 4 + hh] + ad;
        l0 = (l0 >= 0.f) ? l0 : 0.2f * l0;
        float e0 = __expf(l0);
        half4 h0 = *(const half4*)(hbuf + (size_t)s0 * 128 + f);
        den += e0;
        a4.x = fmaf(e0, (float)h0[0], a4.x); a4.y = fmaf(e0, (float)h0[1], a4.y);
        a4.z = fmaf(e0, (float)h0[2], a4.z); a4.w = fmaf(e0, (float)h0[3], a4.w);
    }

    a4.x += __shfl_xor(a4.x, 32);
    a4.y += __shfl_xor(a4.y, 32);
    a4.z += __shfl_xor(a4.z, 32);
    a4.w += __shfl_xor(a4.w, 32);
    den  += __shfl_xor(den, 32);

    if (half == 0) {
        float rd = 1.f / fmaxf(den, 1e-16f);
        float4 bv = *(const float4*)(b + f);
        float x0 = a4.x * rd + bv.x;
        float x1 = a4.y * rd + bv.y;
        float x2 = a4.z * rd + bv.z;
        float x3 = a4.w * rd + bv.w;
        x0 = (x0 > 0.f) ? x0 : expm1f(x0);
        x1 = (x1 > 0.f) ? x1 : expm1f(x1);
        x2 = (x2 > 0.f) ? x2 : expm1f(x2);
        x3 = (x3 > 0.f) ? x3 : expm1f(x3);
        if (F16OUT) {
            half4 hv = {(_Float16)x0, (_Float16)x1, (_Float16)x2, (_Float16)x3};
            *(half4*)(out16 + (size_t)node * 128 + f) = hv;
        } else {
            *(float4*)(out32 + (size_t)node * 128 + f) = make_float4(x0, x1, x2, x3);
        }
    }
}

extern "C" void kernel_launch(void* const* d_in, const int* in_sizes, int n_in,
                              void* d_out, int out_size, void* d_ws, size_t ws_size,
                              hipStream_t stream) {
    const float* X    = (const float*)d_in[0];
    const int*   ei   = (const int*)d_in[1];
    const float* W0   = (const float*)d_in[2];
    const float* as0  = (const float*)d_in[3];
    const float* ad0  = (const float*)d_in[4];
    const float* b0   = (const float*)d_in[5];
    const float* W1   = (const float*)d_in[6];
    const float* as1  = (const float*)d_in[7];
    const float* ad1  = (const float*)d_in[8];
    const float* b1   = (const float*)d_in[9];

    const int* srcp = ei;            // edge_index[0]
    const int* dstp = ei + NEDGES;   // edge_index[1]

    _Float16* X16  = (_Float16*)d_ws;            // 6.4M halves
    _Float16* h16  = X16 + 6400000;              // 6.4M halves
    _Float16* ho16 = h16 + 6400000;              // 6.4M halves (layer-1 out)
    _Float16* W0t  = ho16 + 6400000;             // 16384
    _Float16* W1t  = W0t + 16384;                // 16384
    float* as_ = (float*)(W1t + 16384);          // 200,000
    float* ad_ = as_ + 200000;                   // 200,000
    unsigned* binned = (unsigned*)(ad_ + 200000);        // (KB+1)*CAPB
    int*  csr_src   = (int*)(binned + (KB + 1) * CAPB);  // KB*CAPB
    int2* node_info = (int2*)(csr_src + KB * CAPB);      // 50,000
    int*  bincur    = (int*)(node_info + NNODES);        // KB

    // ---- CSR build (two-pass LDS binning), layer-invariant ----
    bininit_kernel<<<1, 256, 0, stream>>>(bincur);
    binA_kernel<<<NABLK, 256, 0, stream>>>(srcp, dstp, bincur, binned);
    binB_kernel<<<KB, 256, 0, stream>>>(binned, bincur, csr_src, node_info);

    // ---- fp16 conversions (X, W0^T, W1^T) ----
    prep_kernel<<<2048, 256, 0, stream>>>(X, W0, W1, X16, W0t, W1t);

    const int NODE_BLOCKS = (NNODES + 3) / 4;
    const int GEMM_BLOCKS = (NNODES + 63) / 64;

    // layer 0
    gemm_mfma_kernel<<<GEMM_BLOCKS, 256, 0, stream>>>(
        X16, W0t, as0, ad0, h16, as_, ad_, NNODES);
    att_gather_kernel<true><<<NODE_BLOCKS, 256, 0, stream>>>(
        csr_src, node_info, as_, ad_, h16, b0, nullptr, ho16);

    // layer 1
    gemm_mfma_kernel<<<GEMM_BLOCKS, 256, 0, stream>>>(
        ho16, W1t, as1, ad1, h16, as_, ad_, NNODES);
    att_gather_kernel<false><<<NODE_BLOCKS, 256, 0, stream>>>(
        csr_src, node_info, as_, ad_, h16, b1, (float*)d_out, nullptr);
}

// Round 13
// 156.540 us; speedup vs baseline: 3.1708x; 1.0234x over previous
//
#include <hip/hip_runtime.h>
#include <math.h>
#include <float.h>

#define NNODES 50000
#define NEDGES 800000
// feature dims: in=hid=out=128, heads=4, head_dim=32

// ---- CSR binning params ----
#define KB    196                       // coarse bins (dst>>8), covers 50176 nodes
#define NPB   256                       // nodes per bin
#define CAPB  4608                      // per-bin capacity (mean 4081, +8 sigma)
#define EPB   4096                      // edges per pass-A block
#define NABLK ((NEDGES + EPB - 1) / EPB)   // 196

typedef __attribute__((ext_vector_type(4))) _Float16 half4;
typedef __attribute__((ext_vector_type(8))) _Float16 half8;
typedef __attribute__((ext_vector_type(4))) float f32x4;

// ---------------- CSR build, two-pass LDS binning ----------------
__global__ __launch_bounds__(256) void bininit_kernel(int* __restrict__ bincur) {
    int t = threadIdx.x;
    if (t < KB) bincur[t] = t * CAPB;
}

__global__ __launch_bounds__(256) void binA_kernel(
    const int* __restrict__ src, const int* __restrict__ dst,
    int* __restrict__ bincur, unsigned* __restrict__ binned)
{
    __shared__ int lhist[KB];
    __shared__ int lstart[KB];
    __shared__ int lcur[KB];
    __shared__ int gbase[KB];
    __shared__ unsigned lbuf[EPB];
    __shared__ int wtot[4];

    int t = threadIdx.x;
    int e0 = blockIdx.x * EPB;
    int ecnt = NEDGES - e0; if (ecnt > EPB) ecnt = EPB;

    for (int b = t; b < KB; b += 256) lhist[b] = 0;
    __syncthreads();

    for (int idx = t; idx < ecnt; idx += 256)
        atomicAdd(&lhist[((unsigned)dst[e0 + idx]) >> 8], 1);
    __syncthreads();

    {
        int lane = t & 63, w = t >> 6;
        int v = (t < KB) ? lhist[t] : 0;
        int x = v;
#pragma unroll
        for (int off = 1; off < 64; off <<= 1) {
            int y = __shfl_up(x, off, 64);
            if (lane >= off) x += y;
        }
        if (lane == 63) wtot[w] = x;
        __syncthreads();
        int wpre = 0;
#pragma unroll
        for (int j = 0; j < 4; ++j) if (j < w) wpre += wtot[j];
        int ex = wpre + x - v;
        if (t < KB) { lstart[t] = ex; lcur[t] = ex; }
    }
    __syncthreads();

    if (t < KB) {
        int c = lhist[t];
        gbase[t] = c ? atomicAdd(&bincur[t], c) : 0;
    }
    __syncthreads();

    for (int idx = t; idx < ecnt; idx += 256) {
        unsigned d = (unsigned)dst[e0 + idx];
        unsigned s = (unsigned)src[e0 + idx];
        int pos = atomicAdd(&lcur[d >> 8], 1);
        lbuf[pos] = (d << 16) | s;
    }
    __syncthreads();

    for (int idx = t; idx < ecnt; idx += 256) {
        unsigned p = lbuf[idx];
        int b = p >> 24;
        binned[gbase[b] + (idx - lstart[b])] = p;
    }
}

__global__ __launch_bounds__(256) void binB_kernel(
    const unsigned* __restrict__ binned, const int* __restrict__ bincur,
    int* __restrict__ csr_src, int2* __restrict__ node_info)
{
    __shared__ int lhist[NPB];
    __shared__ int lcur[NPB];
    __shared__ int wtot[4];
    int k = blockIdx.x;
    int t = threadIdx.x;
    int base = k * CAPB;
    int cnt = bincur[k] - base;

    lhist[t] = 0;
    __syncthreads();

    for (int i = t; i < cnt; i += 256)
        atomicAdd(&lhist[(binned[base + i] >> 16) & 0xFF], 1);
    __syncthreads();

    int lane = t & 63, w = t >> 6;
    int v = lhist[t];
    int x = v;
#pragma unroll
    for (int off = 1; off < 64; off <<= 1) {
        int y = __shfl_up(x, off, 64);
        if (lane >= off) x += y;
    }
    if (lane == 63) wtot[w] = x;
    __syncthreads();
    int wpre = 0;
#pragma unroll
    for (int j = 0; j < 4; ++j) if (j < w) wpre += wtot[j];
    int ex = wpre + x - v;
    lcur[t] = ex;
    int node = k * NPB + t;
    if (node < NNODES) node_info[node] = make_int2(base + ex, v);
    __syncthreads();

    for (int i = t; i < cnt; i += 256) {
        unsigned p = binned[base + i];
        int ln = (p >> 16) & 0xFF;
        int pos = atomicAdd(&lcur[ln], 1);
        csr_src[base + pos] = (int)(p & 0xFFFFu);
    }
}

// ---------------- prep: W0/W1 -> fp16 transposed [col][k] -------
__global__ __launch_bounds__(256) void prepw_kernel(
    const float* __restrict__ W0, const float* __restrict__ W1,
    _Float16* __restrict__ W0t, _Float16* __restrict__ W1t)
{
    int idx = blockIdx.x * 256 + threadIdx.x;
    if (idx < 128 * 128) {
        int cc = idx >> 7, k = idx & 127;
        W0t[idx] = (_Float16)W0[k * 128 + cc];
        W1t[idx] = (_Float16)W1[k * 128 + cc];
    }
}

// ---------------- MFMA GEMM + alpha: h = A@W ; alpha_s/d = <h, a_*> -------
// A [nrows][128] fp32 (layer 0, converted during staging) or fp16 (layer 1);
// Wt fp16 [128 cols][128 k]. Block = 256 thr = 4 waves; tile 64 x 128.
// v_mfma_f32_16x16x32_f16 frag mapping as verified in round 12.
#define GP 136
template <bool F32IN>
__global__ __launch_bounds__(256) void gemm_mfma_kernel(
    const void* __restrict__ Ain, const _Float16* __restrict__ Wt,
    const float* __restrict__ avs, const float* __restrict__ avd,
    _Float16* __restrict__ Hh, float* __restrict__ alpha_s,
    float* __restrict__ alpha_d, int nrows)
{
    __shared__ _Float16 Xs[64 * GP];    // 17.0 KB
    __shared__ _Float16 Ws[128 * GP];   // 34.0 KB

    int t = threadIdx.x;
    int brow = blockIdx.x * 64;

    // stage A rows: thread t -> row t>>2, 32-element chunk q = t&3
    {
        int r = t >> 2, q = t & 3;
        int grow = brow + r;
        _Float16* d = Xs + r * GP + q * 32;
        if (F32IN) {
            const float* A32 = (const float*)Ain;
            float4 v[8];
#pragma unroll
            for (int j = 0; j < 8; ++j) v[j] = make_float4(0, 0, 0, 0);
            if (grow < nrows) {
                const float4* p = (const float4*)(A32 + (size_t)grow * 128 + q * 32);
#pragma unroll
                for (int j = 0; j < 8; ++j) v[j] = p[j];
            }
#pragma unroll
            for (int j = 0; j < 8; ++j) {
                half4 h = {(_Float16)v[j].x, (_Float16)v[j].y,
                           (_Float16)v[j].z, (_Float16)v[j].w};
                *(half4*)(d + j * 4) = h;
            }
        } else {
            const _Float16* A16 = (const _Float16*)Ain;
            half8 v0 = {}, v1 = {}, v2 = {}, v3 = {};
            if (grow < nrows) {
                const half8* p = (const half8*)(A16 + (size_t)grow * 128 + q * 32);
                v0 = p[0]; v1 = p[1]; v2 = p[2]; v3 = p[3];
            }
            *(half8*)(d + 0)  = v0; *(half8*)(d + 8)  = v1;
            *(half8*)(d + 16) = v2; *(half8*)(d + 24) = v3;
        }
    }
    // stage Wt (128 x 256B = 32KB): thread t -> row t>>1, 128B half t&1
    {
        int wr = t >> 1, wh = t & 1;
        const half8* p = (const half8*)(Wt + wr * 128 + wh * 64);
        _Float16* d = Ws + wr * GP + wh * 64;
#pragma unroll
        for (int j = 0; j < 8; ++j) *(half8*)(d + j * 8) = p[j];
    }
    __syncthreads();

    int wv = t >> 6, l = t & 63;
    int lrow = l & 15;
    int lk8  = (l >> 4) * 8;

    f32x4 acc[8];
#pragma unroll
    for (int n = 0; n < 8; ++n) acc[n] = (f32x4){0.f, 0.f, 0.f, 0.f};

    const _Float16* xbase = Xs + (wv * 16 + lrow) * GP + lk8;
#pragma unroll
    for (int kk = 0; kk < 4; ++kk) {
        half8 a = *(const half8*)(xbase + kk * 32);
#pragma unroll
        for (int n = 0; n < 8; ++n) {
            half8 bf = *(const half8*)(Ws + (n * 16 + lrow) * GP + kk * 32 + lk8);
            acc[n] = __builtin_amdgcn_mfma_f32_16x16x32_f16(a, bf, acc[n], 0, 0, 0);
        }
    }

    // epilogue: h16 stores + fused alpha dot products
    int c = lrow;
    int g = l >> 4;
#pragma unroll
    for (int n = 0; n < 8; ++n) {
#pragma unroll
        for (int r = 0; r < 4; ++r) {
            int row = brow + wv * 16 + g * 4 + r;
            if (row < nrows)
                Hh[(size_t)row * 128 + n * 16 + c] = (_Float16)acc[n][r];
        }
    }
#pragma unroll
    for (int hd = 0; hd < 4; ++hd) {
        float as0 = avs[hd * 32 + c], as1 = avs[hd * 32 + 16 + c];
        float ad0 = avd[hd * 32 + c], ad1 = avd[hd * 32 + 16 + c];
#pragma unroll
        for (int r = 0; r < 4; ++r) {
            float ps = acc[2 * hd][r] * as0 + acc[2 * hd + 1][r] * as1;
            float pd = acc[2 * hd][r] * ad0 + acc[2 * hd + 1][r] * ad1;
            ps += __shfl_xor(ps, 1); ps += __shfl_xor(ps, 2);
            ps += __shfl_xor(ps, 4); ps += __shfl_xor(ps, 8);
            pd += __shfl_xor(pd, 1); pd += __shfl_xor(pd, 2);
            pd += __shfl_xor(pd, 4); pd += __shfl_xor(pd, 8);
            if (c == 0) {
                int row = brow + wv * 16 + g * 4 + r;
                if (row < nrows) {
                    alpha_s[row * 4 + hd] = ps;
                    alpha_d[row * 4 + hd] = pd;
                }
            }
        }
    }
}

// ------- fused attention + gather: 4 edge parities x 16 feature lanes ------
// out = elu( (sum_e ex_e * h[src_e]) / (sum_e ex_e) + b ),
// ex_e = exp(leakyrelu(alpha_s[src_e] + alpha_d[node]))  (no max-shift:
// logits O(+-6), exp fp32-safe, softmax shift-invariant).
// One wave per node. p = lane>>4 handles edges i = beg+p, beg+p+4, ...;
// lane owns features ft*8..ft*8+7 (ft = lane&15): 16 lanes x 16B = full 256B
// fp16 h row per edge. One shared-op instruction (csr/alpha/exp) covers 4
// edges; 2-edge unroll -> 8 independent 16B chains per wave. Parity partials
// combined via shfl_xor(16)+shfl_xor(32).
template <bool F16OUT>
__global__ __launch_bounds__(256) void att_gather_kernel(
    const int* __restrict__ csr_src, const int2* __restrict__ node_info,
    const float* __restrict__ alpha_s, const float* __restrict__ alpha_d,
    const _Float16* __restrict__ hbuf, const float* __restrict__ b,
    float* __restrict__ out32, _Float16* __restrict__ out16)
{
    int node = blockIdx.x * 4 + (threadIdx.x >> 6);
    if (node >= NNODES) return;
    int lane = threadIdx.x & 63;
    int p  = lane >> 4;                 // edge parity 0..3
    int ft = lane & 15;                 // feature block
    int f  = ft * 8;                    // features f..f+7
    int hh = ft >> 2;                   // head
    int2 bi = node_info[node];
    int beg = bi.x, end = bi.x + bi.y;
    float ad = alpha_d[node * 4 + hh];

    float acc[8] = {0.f, 0.f, 0.f, 0.f, 0.f, 0.f, 0.f, 0.f};
    float den = 0.f;
    int i = beg + p;
    for (; i + 4 < end; i += 8) {       // 2 independent edges per lane/iter
        int s0 = csr_src[i];
        int s1 = csr_src[i + 4];
        float l0 = alpha_s[s0 * 4 + hh] + ad;
        float l1 = alpha_s[s1 * 4 + hh] + ad;
        half8 h0 = *(const half8*)(hbuf + (size_t)s0 * 128 + f);
        half8 h1 = *(const half8*)(hbuf + (size_t)s1 * 128 + f);
        l0 = fmaxf(l0, 0.2f * l0);      // leaky relu
        l1 = fmaxf(l1, 0.2f * l1);
        float e0 = __expf(l0);
        float e1 = __expf(l1);
        den += e0 + e1;
#pragma unroll
        for (int j = 0; j < 8; ++j) acc[j] = fmaf(e0, (float)h0[j], acc[j]);
#pragma unroll
        for (int j = 0; j < 8; ++j) acc[j] = fmaf(e1, (float)h1[j], acc[j]);
    }
    for (; i < end; i += 4) {           // tail: 0 or 1 edge of this parity
        int s0 = csr_src[i];
        float l0 = alpha_s[s0 * 4 + hh] + ad;
        half8 h0 = *(const half8*)(hbuf + (size_t)s0 * 128 + f);
        l0 = fmaxf(l0, 0.2f * l0);
        float e0 = __expf(l0);
        den += e0;
#pragma unroll
        for (int j = 0; j < 8; ++j) acc[j] = fmaf(e0, (float)h0[j], acc[j]);
    }

    // combine the 4 parities (lane bits 4,5)
#pragma unroll
    for (int j = 0; j < 8; ++j) {
        acc[j] += __shfl_xor(acc[j], 16);
        acc[j] += __shfl_xor(acc[j], 32);
    }
    den += __shfl_xor(den, 16);
    den += __shfl_xor(den, 32);

    if (p == 0) {
        float rd = 1.f / fmaxf(den, 1e-16f);
        float4 bv0 = *(const float4*)(b + f);
        float4 bv1 = *(const float4*)(b + f + 4);
        float x[8];
        x[0] = acc[0] * rd + bv0.x; x[1] = acc[1] * rd + bv0.y;
        x[2] = acc[2] * rd + bv0.z; x[3] = acc[3] * rd + bv0.w;
        x[4] = acc[4] * rd + bv1.x; x[5] = acc[5] * rd + bv1.y;
        x[6] = acc[6] * rd + bv1.z; x[7] = acc[7] * rd + bv1.w;
#pragma unroll
        for (int j = 0; j < 8; ++j) x[j] = (x[j] > 0.f) ? x[j] : expm1f(x[j]);
        if (F16OUT) {
            half8 hv;
#pragma unroll
            for (int j = 0; j < 8; ++j) hv[j] = (_Float16)x[j];
            *(half8*)(out16 + (size_t)node * 128 + f) = hv;
        } else {
            *(float4*)(out32 + (size_t)node * 128 + f) =
                make_float4(x[0], x[1], x[2], x[3]);
            *(float4*)(out32 + (size_t)node * 128 + f + 4) =
                make_float4(x[4], x[5], x[6], x[7]);
        }
    }
}

extern "C" void kernel_launch(void* const* d_in, const int* in_sizes, int n_in,
                              void* d_out, int out_size, void* d_ws, size_t ws_size,
                              hipStream_t stream) {
    const float* X    = (const float*)d_in[0];
    const int*   ei   = (const int*)d_in[1];
    const float* W0   = (const float*)d_in[2];
    const float* as0  = (const float*)d_in[3];
    const float* ad0  = (const float*)d_in[4];
    const float* b0   = (const float*)d_in[5];
    const float* W1   = (const float*)d_in[6];
    const float* as1  = (const float*)d_in[7];
    const float* ad1  = (const float*)d_in[8];
    const float* b1   = (const float*)d_in[9];

    const int* srcp = ei;            // edge_index[0]
    const int* dstp = ei + NEDGES;   // edge_index[1]

    _Float16* h16  = (_Float16*)d_ws;            // 6.4M halves
    _Float16* ho16 = h16 + 6400000;              // 6.4M halves (layer-1 out)
    _Float16* W0t  = ho16 + 6400000;             // 16384
    _Float16* W1t  = W0t + 16384;                // 16384
    float* as_ = (float*)(W1t + 16384);          // 200,000
    float* ad_ = as_ + 200000;                   // 200,000
    unsigned* binned = (unsigned*)(ad_ + 200000);        // (KB+1)*CAPB
    int*  csr_src   = (int*)(binned + (KB + 1) * CAPB);  // KB*CAPB
    int2* node_info = (int2*)(csr_src + KB * CAPB);      // 50,000
    int*  bincur    = (int*)(node_info + NNODES);        // KB

    // ---- CSR build (two-pass LDS binning), layer-invariant ----
    bininit_kernel<<<1, 256, 0, stream>>>(bincur);
    binA_kernel<<<NABLK, 256, 0, stream>>>(srcp, dstp, bincur, binned);
    binB_kernel<<<KB, 256, 0, stream>>>(binned, bincur, csr_src, node_info);

    // ---- W transposes to fp16 ----
    prepw_kernel<<<64, 256, 0, stream>>>(W0, W1, W0t, W1t);

    const int NODE_BLOCKS = (NNODES + 3) / 4;
    const int GEMM_BLOCKS = (NNODES + 63) / 64;

    // layer 0 (fp32 input, converted in staging)
    gemm_mfma_kernel<true><<<GEMM_BLOCKS, 256, 0, stream>>>(
        X, W0t, as0, ad0, h16, as_, ad_, NNODES);
    att_gather_kernel<true><<<NODE_BLOCKS, 256, 0, stream>>>(
        csr_src, node_info, as_, ad_, h16, b0, nullptr, ho16);

    // layer 1 (fp16 input from layer-0 output)
    gemm_mfma_kernel<false><<<GEMM_BLOCKS, 256, 0, stream>>>(
        ho16, W1t, as1, ad1, h16, as_, ad_, NNODES);
    att_gather_kernel<false><<<NODE_BLOCKS, 256, 0, stream>>>(
        csr_src, node_info, as_, ad_, h16, b1, (float*)d_out, nullptr);
}